// Round 10
// baseline (318.268 us; speedup 1.0000x reference)
//
#include <hip/hip_runtime.h>
#include <hip/hip_bf16.h>
#include <cstdint>
#include <cstddef>

#define BB   8
#define NN   4096
#define CC   64
#define KK   16
#define H2   128
#define NPOSF 524288.0f
#define BNEPS 1e-5f

typedef __attribute__((ext_vector_type(8))) short  short8;
typedef __attribute__((ext_vector_type(4))) float  f32x4;

#define MFMA(a,b,c) __builtin_amdgcn_mfma_f32_16x16x32_bf16(a, b, c, 0, 0, 0)

// ---------- helpers ----------
__device__ __forceinline__ unsigned short f2bf(float x) {
  union { float f; unsigned u; } v; v.f = x;
  unsigned u = v.u;
  return (unsigned short)((u + 0x7fffu + ((u >> 16) & 1u)) >> 16);
}
__device__ __forceinline__ float bf2f(unsigned short h) {
  union { unsigned u; float f; } v; v.u = ((unsigned)h) << 16; return v.f;
}
__device__ __forceinline__ unsigned long long shflxor64(unsigned long long v, int j) {
  unsigned lo = (unsigned)v, hi = (unsigned)(v >> 32);
  lo = (unsigned)__shfl_xor((int)lo, j);
  hi = (unsigned)__shfl_xor((int)hi, j);
  return ((unsigned long long)hi << 32) | lo;
}
__device__ __forceinline__ unsigned long long shfl64(unsigned long long v, int src) {
  unsigned lo = (unsigned)v, hi = (unsigned)(v >> 32);
  lo = (unsigned)__shfl((int)lo, src);
  hi = (unsigned)__shfl((int)hi, src);
  return ((unsigned long long)hi << 32) | lo;
}

// BN param recompute (bit-identical to the old k_finalize), done per consumer block
#define BN_INLINE(S_, Q_, g_, b_, aLds, bLds, CH) \
  if (t < CH) { \
    float s = 0.f, qq = 0.f; \
    for (int c = 0; c < 32; ++c) { s += S_[c*CH + t]; qq += Q_[c*CH + t]; } \
    float mean = s * (1.0f / NPOSF); \
    float var  = qq * (1.0f / NPOSF) - mean*mean; \
    float rs   = 1.0f / sqrtf(var + BNEPS); \
    float a    = g_[t] * rs; \
    aLds[t] = a; bLds[t] = b_[t] - mean*a; \
  }

// ---------- utility kernels ----------
__global__ __launch_bounds__(256) void k_zero(float* p) {
  p[blockIdx.x * 256 + threadIdx.x] = 0.f;
}

// prep: pos2t[b][n] = (x,y,z,x^2+y^2+z^2) (np-pinned rounding) + pos1 passthrough copy
__global__ __launch_bounds__(256) void k_prep(const float* __restrict__ pos2, float4* __restrict__ out,
                                              const float* __restrict__ pos1, float* __restrict__ outP) {
  int i = blockIdx.x * 256 + threadIdx.x;
  int b = i >> 12, n = i & 4095;
  float x = pos2[(b*3 + 0)*NN + n];
  float y = pos2[(b*3 + 1)*NN + n];
  float z = pos2[(b*3 + 2)*NN + n];
  float w = __fadd_rn(__fadd_rn(__fmul_rn(x,x), __fmul_rn(y,y)), __fmul_rn(z,z));
  out[i] = make_float4(x, y, z, w);
  if (i < BB*3*NN/4) {
    *(float4*)(outP + i*4) = *(const float4*)(pos1 + i*4);
  }
}

// [B,64,N] fp32 -> [B,N,64] bf16, both tensors in one launch (z = 2*B)
__global__ __launch_bounds__(256) void k_transposeb2(const float* __restrict__ f2, const float* __restrict__ f1,
                                                     unsigned short* __restrict__ o2, unsigned short* __restrict__ o1) {
  __shared__ float tile[32][33];
  int z = blockIdx.z;
  int b = z & 7;
  const float* in = (z < 8) ? f2 : f1;
  unsigned short* out = (z < 8) ? o2 : o1;
  int n0 = blockIdx.x * 32, c0 = blockIdx.y * 32;
  int tx = threadIdx.x, ty = threadIdx.y;
  #pragma unroll
  for (int i = 0; i < 32; i += 8)
    tile[ty + i][tx] = in[((size_t)(b*CC + c0 + ty + i))*NN + n0 + tx];
  __syncthreads();
  #pragma unroll
  for (int i = 0; i < 32; i += 8)
    out[((size_t)(b*NN + n0 + ty + i))*CC + c0 + tx] = f2bf(tile[tx][ty + i]);
}

// ---------- weight pre-pack: A-fragment order (hi bf16) ----------
__global__ __launch_bounds__(256) void k_wt(const float* __restrict__ W0, const float* __restrict__ W1,
                                            const float* __restrict__ W2, unsigned short* __restrict__ Apk0,
                                            unsigned short* __restrict__ Apk1, unsigned short* __restrict__ Apk2) {
  int i = blockIdx.x * 256 + threadIdx.x;
  if (i < 1280) {            // L0: 4 mt x 5 s x 64 lanes
    int mt = i / 320, r = i % 320, s = r / 64, lane = r % 64;
    int o = mt*16 + (lane & 15), q = lane >> 4, fi = mt*5 + s;
    #pragma unroll
    for (int j = 0; j < 8; ++j) {
      int c = s*32 + q*8 + j;
      float w = 0.f;
      if (c < 131) { int cs = (c < 128) ? (c + 3) : (c - 128); w = W0[o*131 + cs]; }
      Apk0[((size_t)(fi)*64 + lane)*8 + j] = f2bf(w);
    }
  } else if (i < 1792) {     // L1: 4 mt x 2 s
    int k = i - 1280, mt = k / 128, r = k % 128, s = r / 64, lane = r % 64;
    int o = mt*16 + (lane & 15), q = lane >> 4, fi = mt*2 + s;
    #pragma unroll
    for (int j = 0; j < 8; ++j) {
      int c = s*32 + q*8 + j;
      Apk1[((size_t)(fi)*64 + lane)*8 + j] = f2bf(W1[o*64 + c]);
    }
  } else if (i < 2816) {     // L2: 8 mt x 2 s
    int k = i - 1792, mt = k / 128, r = k % 128, s = r / 64, lane = r % 64;
    int o = mt*16 + (lane & 15), q = lane >> 4, fi = mt*2 + s;
    #pragma unroll
    for (int j = 0; j < 8; ++j) {
      int c = s*32 + q*8 + j;
      Apk2[((size_t)(fi)*64 + lane)*8 + j] = f2bf(W2[o*64 + c]);
    }
  }
}

// ---------- KNN pack: A-frags (queries, hi/lo bf16) and B-frags (refs, -2*hi/lo + r2) ----------
__global__ __launch_bounds__(256) void k_packAB(const float* __restrict__ pos1_re,
                                                const float4* __restrict__ pos2t,
                                                unsigned short* __restrict__ ApkQ,
                                                unsigned short* __restrict__ BpkR) {
  int i = blockIdx.x * 256 + threadIdx.x;
  int half = i >> 17;                 // 0: A, 1: B
  int ii = i & 131071;
  int b = ii >> 14, r = ii & 16383;
  int qt = r >> 6, lane = r & 63;
  int li = lane & 15, g = lane >> 4;
  int n = qt*16 + li;
  if (half == 0) {
    float q[3];
    q[0] = pos1_re[(b*3 + 0)*NN + n];
    q[1] = pos1_re[(b*3 + 1)*NN + n];
    q[2] = pos1_re[(b*3 + 2)*NN + n];
    unsigned short qhi[3], qlo[3];
    #pragma unroll
    for (int c = 0; c < 3; ++c) {
      qhi[c] = f2bf(q[c]);
      qlo[c] = f2bf(__fsub_rn(q[c], bf2f(qhi[c])));
    }
    #pragma unroll
    for (int j = 0; j < 8; ++j) {
      int k = g*8 + j;
      unsigned short v = 0;
      if (k < 3)       v = qhi[k];
      else if (k < 6)  v = qhi[k-3];
      else if (k < 9)  v = qlo[k-6];
      else if (k < 11) v = 0x3F80;   // 1.0 bf16
      ApkQ[(((size_t)b*256 + qt)*64 + lane)*8 + j] = v;
    }
  } else {
    float4 rr = pos2t[(size_t)b*NN + n];
    float rc[3] = {rr.x, rr.y, rr.z};
    unsigned short m2hi[3], m2lo[3];
    #pragma unroll
    for (int c = 0; c < 3; ++c) {
      unsigned short rhi = f2bf(rc[c]);
      float rhif = bf2f(rhi);
      m2hi[c] = f2bf(-2.f * rhif);
      unsigned short rlo = f2bf(__fsub_rn(rc[c], rhif));
      m2lo[c] = f2bf(-2.f * bf2f(rlo));
    }
    float r2 = rr.w;
    unsigned short r2hi = f2bf(r2);
    unsigned short r2lo = f2bf(__fsub_rn(r2, bf2f(r2hi)));
    #pragma unroll
    for (int j = 0; j < 8; ++j) {
      int k = g*8 + j;
      unsigned short v = 0;
      if (k < 3)       v = m2hi[k];
      else if (k < 6)  v = m2lo[k-3];
      else if (k < 9)  v = m2hi[k-6];
      else if (k == 9) v = r2hi;
      else if (k == 10)v = r2lo;
      BpkR[(((size_t)b*256 + qt)*64 + lane)*8 + j] = v;
    }
  }
}

// ---------- KNN: MFMA distance filter + exact bitonic select (R6-measured-best config) ----------
__global__ __launch_bounds__(512) void k_knnf(const float* __restrict__ pos1_re,
                                              const float4* __restrict__ pos2t,
                                              const unsigned short* __restrict__ ApkQ,
                                              const unsigned short* __restrict__ BpkR,
                                              unsigned short* __restrict__ idxOut) {
  __shared__ unsigned short lists[16*128];   // 4 KB
  __shared__ unsigned cnts[16];
  __shared__ float smin[16][128];            // 8 KB
  __shared__ float thr[16][2];
  const int t = threadIdx.x, lane = t & 63, wv = t >> 6;
  const int b = blockIdx.y;
  const int qt = blockIdx.x;
  const int li = lane & 15, g = lane >> 4;

  if (t < 16) cnts[t] = 0;

  short8 af = *(const short8*)(ApkQ + (((size_t)b*256 + qt)*64 + lane)*8);
  const unsigned short* bq = BpkR + (size_t)b*256*512 + lane*8;   // tile stride 512 shorts

  const f32x4 zero4 = {0,0,0,0};

  // ---- prepass: per-lane min over 8 sampled tiles in this wave's 32-tile range
  float mn[4] = {3e38f, 3e38f, 3e38f, 3e38f};
  const int off = qt & 3;
  #pragma unroll
  for (int s = 0; s < 8; ++s) {
    short8 bf = *(const short8*)(bq + (size_t)(wv*32 + s*4 + off)*512);
    f32x4 a = MFMA(af, bf, zero4);
    #pragma unroll
    for (int rg = 0; rg < 4; ++rg) mn[rg] = fminf(mn[rg], a[rg]);
  }
  #pragma unroll
  for (int rg = 0; rg < 4; ++rg) smin[g*4 + rg][wv*16 + li] = mn[rg];
  __syncthreads();

  // ---- thresholds: wave wv owns rows wv*2, wv*2+1; rank-10 of 64 pair-combined mins
  #pragma unroll 1
  for (int c = 0; c < 2; ++c) {
    const int rr = wv*2 + c;
    float v = fminf(smin[rr][lane], smin[rr][64 + lane]);
    #pragma unroll
    for (int k = 2; k <= 64; k <<= 1)
      #pragma unroll
      for (int j = k>>1; j > 0; j >>= 1) {
        float p = __shfl_xor(v, j);
        bool keepMin = (((lane & j) == 0) == ((lane & k) == 0));
        float mn_ = fminf(v, p), mx_ = fmaxf(v, p);
        v = keepMin ? mn_ : mx_;
      }
    float t10 = __shfl(v, 9);                 // 10th smallest
    if (lane == 0) {
      const int n = qt*16 + rr;
      float qx = pos1_re[(b*3 + 0)*NN + n];
      float qy = pos1_re[(b*3 + 1)*NN + n];
      float qz = pos1_re[(b*3 + 2)*NN + n];
      float q2 = __fadd_rn(__fadd_rn(__fmul_rn(qx,qx), __fmul_rn(qy,qy)), __fmul_rn(qz,qz));
      float eps2 = __fmaf_rn(1.25e-4f, q2 + 64.f, 6e-4f);   // 2*EPS, generous (validated R2)
      thr[rr][0] = t10;
      thr[rr][1] = t10 + eps2;
    }
  }
  __syncthreads();
  float tsr[4], twr[4];
  #pragma unroll
  for (int rg = 0; rg < 4; ++rg) { tsr[rg] = thr[g*4 + rg][0]; twr[rg] = thr[g*4 + rg][1]; }

  // ---- main scan: this wave's 32 tiles, append survivors
  #pragma unroll 4
  for (int s = 0; s < 32; ++s) {
    const int rt = wv*32 + s;
    short8 bf = *(const short8*)(bq + (size_t)rt*512);
    f32x4 a = MFMA(af, bf, zero4);
    bool any = (a[0] < twr[0]) | (a[1] < twr[1]) | (a[2] < twr[2]) | (a[3] < twr[3]);
    if (__ballot(any)) {
      #pragma unroll
      for (int rg = 0; rg < 4; ++rg) {
        if (a[rg] < twr[rg]) {
          unsigned add = (a[rg] < tsr[rg]) ? 1u : 0x10001u;
          unsigned prev = atomicAdd(&cnts[g*4 + rg], add);
          unsigned pos = prev & 0xffffu;
          if (pos < 128u) lists[((g*4 + rg) << 7) | pos] = (unsigned short)((rt << 4) | li);
        }
      }
    }
  }
  __syncthreads();

  // ---- select: wave wv handles queries wv*2, wv*2+1
  const float4* rp = pos2t + (size_t)b*NN;
  #pragma unroll 1
  for (int c = 0; c < 2; ++c) {
    const int qi = wv*2 + c;
    const int n = qt*16 + qi;
    unsigned cw = cnts[qi];
    unsigned cnt = cw & 0xffffu;
    int c0q = (int)cnt - (int)(cw >> 16);

    const float qx = pos1_re[(b*3 + 0)*NN + n];
    const float qy = pos1_re[(b*3 + 1)*NN + n];
    const float qz = pos1_re[(b*3 + 2)*NN + n];
    const float q2 = __fadd_rn(__fadd_rn(__fmul_rn(qx,qx), __fmul_rn(qy,qy)), __fmul_rn(qz,qz));

    if (c0q >= 16 && cnt <= 128u) {
      const unsigned short* lst = &lists[qi << 7];
      unsigned long long key = ~0ull;
      if (lane < (int)cnt) {
        int ix = lst[lane];
        float4 r = rp[ix];
        float dot = __fadd_rn(__fadd_rn(__fmul_rn(qx,r.x), __fmul_rn(qy,r.y)), __fmul_rn(qz,r.z));
        float d   = __fsub_rn(__fadd_rn(q2, r.w), __fmul_rn(2.0f, dot));
        unsigned du = __float_as_uint(d);
        du ^= (du >> 31) ? 0xFFFFFFFFu : 0x80000000u;
        key = ((unsigned long long)du << 16) | (unsigned)ix;
      }
      #pragma unroll
      for (int k = 2; k <= 64; k <<= 1)
        #pragma unroll
        for (int j = k>>1; j > 0; j >>= 1) {
          unsigned long long p = shflxor64(key, j);
          bool keepMin = (((lane & j) == 0) == ((lane & k) == 0));
          unsigned long long mnk = key < p ? key : p, mxk = key < p ? p : key;
          key = keepMin ? mnk : mxk;
        }
      if (cnt > 64u) {
        unsigned long long k2 = ~0ull;
        if (lane + 64 < (int)cnt) {
          int ix = lst[64 + lane];
          float4 r = rp[ix];
          float dot = __fadd_rn(__fadd_rn(__fmul_rn(qx,r.x), __fmul_rn(qy,r.y)), __fmul_rn(qz,r.z));
          float d   = __fsub_rn(__fadd_rn(q2, r.w), __fmul_rn(2.0f, dot));
          unsigned du = __float_as_uint(d);
          du ^= (du >> 31) ? 0xFFFFFFFFu : 0x80000000u;
          k2 = ((unsigned long long)du << 16) | (unsigned)ix;
        }
        #pragma unroll
        for (int k = 2; k <= 64; k <<= 1)
          #pragma unroll
          for (int j = k>>1; j > 0; j >>= 1) {
            unsigned long long p = shflxor64(k2, j);
            bool keepMin = (((lane & j) == 0) == ((lane & k) == 0));
            unsigned long long mnk = k2 < p ? k2 : p, mxk = k2 < p ? p : k2;
            k2 = keepMin ? mnk : mxk;
          }
        unsigned long long pb = shfl64(k2, (15 - lane) & 63);
        key = key < pb ? key : pb;
      }
      if (lane < 16) idxOut[((size_t)(b*NN + n))*KK + lane] = (unsigned short)(key & 0xffffull);
    } else {
      // fallback: verbatim validated full scan
      unsigned bd  = 0xFFFFFFFFu;
      unsigned bix = 0u;
      unsigned tau = 0xFFFFFFFFu;
      for (int it = 0; it < 64; ++it) {
        float4 r = rp[it*64 + lane];
        float dot = __fadd_rn(__fadd_rn(__fmul_rn(qx,r.x), __fmul_rn(qy,r.y)), __fmul_rn(qz,r.z));
        float d   = __fsub_rn(__fadd_rn(q2, r.w), __fmul_rn(2.0f, dot));
        unsigned du = __float_as_uint(d);
        du ^= (du >> 31) ? 0xFFFFFFFFu : 0x80000000u;
        unsigned long long mask = __ballot(du < tau);
        while (mask) {
          const int l = __ffsll((unsigned long long)mask) - 1;
          mask &= (mask - 1);
          const unsigned sd = (unsigned)__builtin_amdgcn_readlane((int)du, l);
          if (sd >= tau) continue;
          const unsigned sidx = (unsigned)(it*64 + l);
          int m = (bd > sd) ? 1 : 0;
          int pm = __builtin_amdgcn_update_dpp(0, m, 0x111, 0xF, 0xF, true);
          unsigned sb = (unsigned)__builtin_amdgcn_update_dpp(0, (int)bd,  0x111, 0xF, 0xF, true);
          unsigned si = (unsigned)__builtin_amdgcn_update_dpp(0, (int)bix, 0x111, 0xF, 0xF, true);
          if (m) { bd = pm ? sb : sd; bix = pm ? si : sidx; }
          tau = (unsigned)__builtin_amdgcn_readlane((int)bd, 15);
        }
      }
      if (lane < 16) idxOut[((size_t)(b*NN + n))*KK + lane] = (unsigned short)bix;
    }
  }
}

// ---------- wave-level deferred stat reduce (once per wave) ----------
#define WAVE_STATS(NMT) { \
  _Pragma("unroll") \
  for (int mt = 0; mt < NMT; ++mt) { \
    _Pragma("unroll") \
    for (int rg = 0; rg < 4; ++rg) { \
      float s_ = sacc[mt][rg], q_ = sqacc[mt][rg]; \
      s_ += __shfl_xor(s_,1); s_ += __shfl_xor(s_,2); s_ += __shfl_xor(s_,4); s_ += __shfl_xor(s_,8); \
      q_ += __shfl_xor(q_,1); q_ += __shfl_xor(q_,2); q_ += __shfl_xor(q_,4); q_ += __shfl_xor(q_,8); \
      if (cl == 0) { atomicAdd(&sS[mt*16 + q*4 + rg], s_); atomicAdd(&sQ[mt*16 + q*4 + rg], q_); } \
    } \
  } }

// ---------- layer 0: gather -> MFMA, reg weights; R10: idx-hoist + gather double-buffer ----------
__global__ __launch_bounds__(256) void k_layer0(
    const unsigned short* __restrict__ nidx, const float4* __restrict__ pos2t,
    const float* __restrict__ pos1, const unsigned short* __restrict__ f2b,
    const unsigned short* __restrict__ f1b, const unsigned short* __restrict__ Apk0,
    unsigned short* __restrict__ Y0, float* __restrict__ gS, float* __restrict__ gQ) {
  __shared__ float sS[64], sQ[64];
  const int t = threadIdx.x, lane = t & 63, wv = t >> 6;
  const int b = blockIdx.y, n0 = blockIdx.x*32 + wv*8;
  const int cl = lane & 15, q = lane >> 4;

  short8 Wr[20];
  #pragma unroll
  for (int f = 0; f < 20; ++f) Wr[f] = *(const short8*)(Apk0 + ((size_t)f*64 + lane)*8);
  if (t < 64) { sS[t] = 0.f; sQ[t] = 0.f; }
  __syncthreads();

  // hoist all idx loads (breaks the idx->gather dependent chain per iteration)
  int mIdx[8];
  #pragma unroll
  for (int p = 0; p < 8; ++p) mIdx[p] = (int)nidx[((size_t)(b*NN + n0 + p))*KK + cl];

  f32x4 sacc[4]  = {{0,0,0,0},{0,0,0,0},{0,0,0,0},{0,0,0,0}};
  f32x4 sqacc[4] = {{0,0,0,0},{0,0,0,0},{0,0,0,0},{0,0,0,0}};

  // prime p=0 gathers
  const unsigned short* f2r0 = f2b + ((size_t)(b*NN + mIdx[0]))*64;
  const unsigned short* f1r0 = f1b + ((size_t)(b*NN + n0))*64;
  short8 x0 = *(const short8*)(f2r0 + q*8);
  short8 x1 = *(const short8*)(f2r0 + 32 + q*8);
  short8 x2 = *(const short8*)(f1r0 + q*8);
  short8 x3 = *(const short8*)(f1r0 + 32 + q*8);

  #pragma unroll 1
  for (int p = 0; p < 8; ++p) {
    const int n = n0 + p;
    const int m = mIdx[p];
    // prefetch next-p gathers (addresses known: mIdx hoisted)
    short8 nx0, nx1, nx2, nx3;
    if (p < 7) {
      const unsigned short* f2rn = f2b + ((size_t)(b*NN + mIdx[p+1]))*64;
      const unsigned short* f1rn = f1b + ((size_t)(b*NN + n + 1))*64;
      nx0 = *(const short8*)(f2rn + q*8);
      nx1 = *(const short8*)(f2rn + 32 + q*8);
      nx2 = *(const short8*)(f1rn + q*8);
      nx3 = *(const short8*)(f1rn + 32 + q*8);
    }
    short8 x4 = {0,0,0,0,0,0,0,0};
    if (q == 0) {
      float4 pp = pos2t[(size_t)b*NN + m];
      float px = pos1[(b*3 + 0)*NN + n];
      float py = pos1[(b*3 + 1)*NN + n];
      float pz = pos1[(b*3 + 2)*NN + n];
      x4[0] = (short)f2bf(pp.x - px);
      x4[1] = (short)f2bf(pp.y - py);
      x4[2] = (short)f2bf(pp.z - pz);
    }
    f32x4 acc[4] = {{0,0,0,0},{0,0,0,0},{0,0,0,0},{0,0,0,0}};
    #pragma unroll
    for (int mt = 0; mt < 4; ++mt) {
      acc[mt] = MFMA(Wr[mt*5 + 0], x0, acc[mt]);
      acc[mt] = MFMA(Wr[mt*5 + 1], x1, acc[mt]);
      acc[mt] = MFMA(Wr[mt*5 + 2], x2, acc[mt]);
      acc[mt] = MFMA(Wr[mt*5 + 3], x3, acc[mt]);
      acc[mt] = MFMA(Wr[mt*5 + 4], x4, acc[mt]);
    }
    unsigned short* yr = Y0 + (((size_t)(b*NN + n))*KK + cl)*64;
    #pragma unroll
    for (int mt = 0; mt < 4; ++mt) {
      sacc[mt]  += acc[mt];
      sqacc[mt] += acc[mt]*acc[mt];
      ushort4 pk; pk.x = f2bf(acc[mt][0]); pk.y = f2bf(acc[mt][1]);
      pk.z = f2bf(acc[mt][2]); pk.w = f2bf(acc[mt][3]);
      *(ushort4*)(yr + mt*16 + q*4) = pk;
    }
    x0 = nx0; x1 = nx1; x2 = nx2; x3 = nx3;
  }
  WAVE_STATS(4)
  __syncthreads();
  const int slot = blockIdx.x & 31;
  if (t < 64) { atomicAdd(&gS[slot*64 + t], sS[t]); atomicAdd(&gQ[slot*64 + t], sQ[t]); }
}

// ---------- layer 1: inline-bn0(S0,Q0)+relu(Y0) -> MFMA; R10: Y-row double-buffer ----------
__global__ __launch_bounds__(256) void k_layer1(
    const unsigned short* __restrict__ Y0, const float* __restrict__ S0, const float* __restrict__ Q0,
    const float* __restrict__ g0, const float* __restrict__ b0,
    const unsigned short* __restrict__ Apk1, unsigned short* __restrict__ Y1,
    float* __restrict__ gS, float* __restrict__ gQ) {
  __shared__ float sS[64], sQ[64];
  __shared__ float aL[64], bL[64];
  const int t = threadIdx.x, lane = t & 63, wv = t >> 6;
  const int b = blockIdx.y, n0 = blockIdx.x*32 + wv*8;
  const int cl = lane & 15, q = lane >> 4;

  short8 Wr[8];
  #pragma unroll
  for (int f = 0; f < 8; ++f) Wr[f] = *(const short8*)(Apk1 + ((size_t)f*64 + lane)*8);
  BN_INLINE(S0, Q0, g0, b0, aL, bL, 64)
  if (t >= 64 && t < 128) { sS[t-64] = 0.f; sQ[t-64] = 0.f; }
  __syncthreads();

  float ar[16], br[16];
  #pragma unroll
  for (int s = 0; s < 2; ++s)
    #pragma unroll
    for (int j = 0; j < 8; ++j) { int c = s*32 + q*8 + j; ar[s*8+j] = aL[c]; br[s*8+j] = bL[c]; }

  f32x4 sacc[4]  = {{0,0,0,0},{0,0,0,0},{0,0,0,0},{0,0,0,0}};
  f32x4 sqacc[4] = {{0,0,0,0},{0,0,0,0},{0,0,0,0},{0,0,0,0}};

  const unsigned short* yrB = Y0 + (((size_t)(b*NN + n0))*KK + cl)*64;   // +1024 shorts per n
  short8 u0 = *(const short8*)(yrB + q*8);
  short8 u1 = *(const short8*)(yrB + 32 + q*8);

  #pragma unroll 1
  for (int p = 0; p < 8; ++p) {
    const int n = n0 + p;
    short8 v0, v1;
    if (p < 7) {
      const unsigned short* yn = yrB + (size_t)(p + 1)*KK*64;
      v0 = *(const short8*)(yn + q*8);
      v1 = *(const short8*)(yn + 32 + q*8);
    }
    short8 x0, x1;
    #pragma unroll
    for (int j = 0; j < 8; ++j) {
      x0[j] = (short)f2bf(fmaxf(bf2f((unsigned short)u0[j])*ar[j]   + br[j],   0.f));
      x1[j] = (short)f2bf(fmaxf(bf2f((unsigned short)u1[j])*ar[8+j] + br[8+j], 0.f));
    }
    f32x4 acc[4] = {{0,0,0,0},{0,0,0,0},{0,0,0,0},{0,0,0,0}};
    #pragma unroll
    for (int mt = 0; mt < 4; ++mt) {
      acc[mt] = MFMA(Wr[mt*2 + 0], x0, acc[mt]);
      acc[mt] = MFMA(Wr[mt*2 + 1], x1, acc[mt]);
    }
    unsigned short* yw = Y1 + (((size_t)(b*NN + n))*KK + cl)*64;
    #pragma unroll
    for (int mt = 0; mt < 4; ++mt) {
      sacc[mt]  += acc[mt];
      sqacc[mt] += acc[mt]*acc[mt];
      ushort4 pk; pk.x = f2bf(acc[mt][0]); pk.y = f2bf(acc[mt][1]);
      pk.z = f2bf(acc[mt][2]); pk.w = f2bf(acc[mt][3]);
      *(ushort4*)(yw + mt*16 + q*4) = pk;
    }
    u0 = v0; u1 = v1;
  }
  WAVE_STATS(4)
  __syncthreads();
  const int slot = blockIdx.x & 31;
  if (t < 64) { atomicAdd(&gS[slot*64 + t], sS[t]); atomicAdd(&gQ[slot*64 + t], sQ[t]); }
}

// ---------- layer 2 stats + extrema: inline-bn1 + relu -> MFMA(x,W); R10: Y-row double-buffer ----------
__global__ __launch_bounds__(256) void k_l2stats(
    const unsigned short* __restrict__ Y1, const float* __restrict__ S1, const float* __restrict__ Q1,
    const float* __restrict__ g1, const float* __restrict__ b1,
    const unsigned short* __restrict__ Apk2, float2* __restrict__ Ypk,
    float* __restrict__ gS, float* __restrict__ gQ) {
  __shared__ float sS[128], sQ[128];
  __shared__ float aL[64], bL[64];
  const int t = threadIdx.x, lane = t & 63, wv = t >> 6;
  const int b = blockIdx.y, n0 = blockIdx.x*32 + wv*8;
  const int cl = lane & 15, q = lane >> 4;

  short8 Wr[16];
  #pragma unroll
  for (int f = 0; f < 16; ++f) Wr[f] = *(const short8*)(Apk2 + ((size_t)f*64 + lane)*8);
  BN_INLINE(S1, Q1, g1, b1, aL, bL, 64)
  if (t >= 64 && t < 192) { sS[t-64] = 0.f; sQ[t-64] = 0.f; }
  __syncthreads();

  float ar[16], br[16];
  #pragma unroll
  for (int s = 0; s < 2; ++s)
    #pragma unroll
    for (int j = 0; j < 8; ++j) { int c = s*32 + q*8 + j; ar[s*8+j] = aL[c]; br[s*8+j] = bL[c]; }

  float ssum[8] = {0,0,0,0,0,0,0,0};
  float sqsum[8] = {0,0,0,0,0,0,0,0};

  const unsigned short* yrB = Y1 + (((size_t)(b*NN + n0))*KK + cl)*64;
  short8 u0 = *(const short8*)(yrB + q*8);
  short8 u1 = *(const short8*)(yrB + 32 + q*8);

  #pragma unroll 1
  for (int p = 0; p < 8; ++p) {
    const int n = n0 + p;
    short8 v0, v1;
    if (p < 7) {
      const unsigned short* yn = yrB + (size_t)(p + 1)*KK*64;
      v0 = *(const short8*)(yn + q*8);
      v1 = *(const short8*)(yn + 32 + q*8);
    }
    short8 x0, x1;
    #pragma unroll
    for (int j = 0; j < 8; ++j) {
      x0[j] = (short)f2bf(fmaxf(bf2f((unsigned short)u0[j])*ar[j]   + br[j],   0.f));
      x1[j] = (short)f2bf(fmaxf(bf2f((unsigned short)u1[j])*ar[8+j] + br[8+j], 0.f));
    }
    float2* yw = Ypk + ((size_t)(b*NN + n))*H2;
    #pragma unroll
    for (int mt = 0; mt < 8; ++mt) {
      f32x4 acc = {0,0,0,0};
      acc = MFMA(x0, Wr[mt*2 + 0], acc);     // swapped: D[k][ch]
      acc = MFMA(x1, Wr[mt*2 + 1], acc);
      ssum[mt]  += (acc[0] + acc[1]) + (acc[2] + acc[3]);
      sqsum[mt] += acc[0]*acc[0] + acc[1]*acc[1] + acc[2]*acc[2] + acc[3]*acc[3];
      float mx = fmaxf(fmaxf(acc[0], acc[1]), fmaxf(acc[2], acc[3]));
      float mn = fminf(fminf(acc[0], acc[1]), fminf(acc[2], acc[3]));
      mx = fmaxf(mx, __shfl_xor(mx, 16)); mx = fmaxf(mx, __shfl_xor(mx, 32));
      mn = fminf(mn, __shfl_xor(mn, 16)); mn = fminf(mn, __shfl_xor(mn, 32));
      if (lane < 16) yw[mt*16 + lane] = make_float2(mx, mn);
    }
    u0 = v0; u1 = v1;
  }
  #pragma unroll
  for (int mt = 0; mt < 8; ++mt) {
    float s_ = ssum[mt], q_ = sqsum[mt];
    s_ += __shfl_xor(s_, 16); s_ += __shfl_xor(s_, 32);
    q_ += __shfl_xor(q_, 16); q_ += __shfl_xor(q_, 32);
    if (lane < 16) { atomicAdd(&sS[mt*16 + cl], s_); atomicAdd(&sQ[mt*16 + cl], q_); }
  }
  __syncthreads();
  const int slot = blockIdx.x & 31;
  if (t < 128) { atomicAdd(&gS[slot*128 + t], sS[t]); atomicAdd(&gQ[slot*128 + t], sQ[t]); }
}

// ---------- final: inline-bn2(S2,Q2) + relu + (k-max via stored extrema) -> out ----------
__global__ __launch_bounds__(256) void k_bnmax(
    const float2* __restrict__ Ypk, const float* __restrict__ S2, const float* __restrict__ Q2,
    const float* __restrict__ g2, const float* __restrict__ b2,
    float* __restrict__ outF) {
  __shared__ float a2s[128], b2s[128];
  __shared__ float oBuf[32*128];   // 16 KB [np][ch]
  const int t = threadIdx.x;
  const int b = blockIdx.y, nb = blockIdx.x*32;
  BN_INLINE(S2, Q2, g2, b2, a2s, b2s, 128)
  __syncthreads();

  const float2* src = Ypk + ((size_t)(b*NN + nb))*H2;
  #pragma unroll
  for (int e = 0; e < 16; ++e) {
    int i = e*256 + t;
    float2 v = src[i];
    int ch = i & 127;
    float a = a2s[ch];
    float sel = (a >= 0.f) ? v.x : v.y;
    oBuf[i] = fmaxf(sel*a + b2s[ch], 0.f);
  }
  __syncthreads();
  {
    const int ch = t & 127, npb = (t >> 7) * 16;
    #pragma unroll
    for (int g = 0; g < 4; ++g) {
      float4 v = make_float4(oBuf[(npb + g*4 + 0)*128 + ch],
                             oBuf[(npb + g*4 + 1)*128 + ch],
                             oBuf[(npb + g*4 + 2)*128 + ch],
                             oBuf[(npb + g*4 + 3)*128 + ch]);
      *(float4*)(outF + ((size_t)(b*H2 + ch))*NN + nb + npb + g*4) = v;
    }
  }
}

// ---------- launch ----------
extern "C" void kernel_launch(void* const* d_in, const int* in_sizes, int n_in,
                              void* d_out, int out_size, void* d_ws, size_t ws_size,
                              hipStream_t stream) {
  const float* pos1    = (const float*)d_in[0];
  const float* pos1_re = (const float*)d_in[1];
  const float* pos2    = (const float*)d_in[2];
  const float* f1      = (const float*)d_in[3];
  const float* f2      = (const float*)d_in[4];
  const float* W0 = (const float*)d_in[6];
  const float* g0 = (const float*)d_in[7];
  const float* b0 = (const float*)d_in[8];
  const float* W1 = (const float*)d_in[9];
  const float* g1 = (const float*)d_in[10];
  const float* b1 = (const float*)d_in[11];
  const float* W2 = (const float*)d_in[12];
  const float* g2 = (const float*)d_in[13];
  const float* b2 = (const float*)d_in[14];
  float* out = (float*)d_out;

  // workspace layout (bytes)
  char* ws = (char*)d_ws;
  float* stats = (float*)ws;                 // 65536 B
  float* S0 = stats;         float* Q0 = stats + 2048;
  float* S1 = stats + 4096;  float* Q1 = stats + 6144;
  float* S2 = stats + 8192;  float* Q2 = stats + 12288;
  unsigned short* Apk0 = (unsigned short*)(ws + 67584);    // 20480 B (hi only used)
  unsigned short* Apk1 = (unsigned short*)(ws + 108544);   // 8192 B used
  unsigned short* Apk2 = (unsigned short*)(ws + 124928);   // 16384 B used
  unsigned short* idxb = (unsigned short*)(ws + 157696);   // 1 MB
  float4* pos2t        = (float4*)(ws + 1206272);          // 512 KB
  unsigned short* f2b  = (unsigned short*)(ws + 1730560);  // 4 MB
  unsigned short* f1b  = (unsigned short*)(ws + 5924864);  // 4 MB
  unsigned short* Y0   = (unsigned short*)(ws + 10119168); // 64 MB
  unsigned short* Y1   = (unsigned short*)(ws + 77228032); // 64 MB -> 144336896
  // KNN pack buffers alias the Y0 region (dead until k_layer0 runs, stream-ordered)
  unsigned short* ApkQ = (unsigned short*)(ws + 10119168);            // 2 MB
  unsigned short* BpkR = (unsigned short*)(ws + 10119168 + 2097152);  // 2 MB
  // y2 extrema pairs alias the Y0 region too (Y0 dead after k_layer1): 32 MB
  float2* Ypk          = (float2*)(ws + 10119168);
  if (ws_size < 144336896u) return;

  k_zero<<<dim3(64), 256, 0, stream>>>(stats);
  k_wt<<<dim3(11), 256, 0, stream>>>(W0, W1, W2, Apk0, Apk1, Apk2);
  k_prep<<<dim3(BB*NN/256), 256, 0, stream>>>(pos2, pos2t, pos1, out);
  k_packAB<<<dim3(1024), 256, 0, stream>>>(pos1_re, pos2t, ApkQ, BpkR);
  k_transposeb2<<<dim3(NN/32, CC/32, 2*BB), dim3(32, 8), 0, stream>>>(f2, f1, f2b, f1b);
  k_knnf<<<dim3(256, BB), 512, 0, stream>>>(pos1_re, pos2t, ApkQ, BpkR, idxb);

  k_layer0<<<dim3(NN/32, BB), 256, 0, stream>>>(idxb, pos2t, pos1, f2b, f1b, Apk0, Y0, S0, Q0);
  k_layer1<<<dim3(NN/32, BB), 256, 0, stream>>>(Y0, S0, Q0, g0, b0, Apk1, Y1, S1, Q1);
  k_l2stats<<<dim3(NN/32, BB), 256, 0, stream>>>(Y1, S1, Q1, g1, b1, Apk2, Ypk, S2, Q2);
  k_bnmax<<<dim3(NN/32, BB), 256, 0, stream>>>(Ypk, S2, Q2, g2, b2, out + (size_t)BB*3*NN);
}

// Round 11
// 312.308 us; speedup vs baseline: 1.0191x; 1.0191x over previous
//
#include <hip/hip_runtime.h>
#include <hip/hip_bf16.h>
#include <cstdint>
#include <cstddef>

#define BB   8
#define NN   4096
#define CC   64
#define KK   16
#define H2   128
#define NPOSF 524288.0f
#define BNEPS 1e-5f

typedef __attribute__((ext_vector_type(8))) short  short8;
typedef __attribute__((ext_vector_type(4))) float  f32x4;

#define MFMA(a,b,c) __builtin_amdgcn_mfma_f32_16x16x32_bf16(a, b, c, 0, 0, 0)

// ---------- helpers ----------
__device__ __forceinline__ unsigned short f2bf(float x) {
  union { float f; unsigned u; } v; v.f = x;
  unsigned u = v.u;
  return (unsigned short)((u + 0x7fffu + ((u >> 16) & 1u)) >> 16);
}
__device__ __forceinline__ float bf2f(unsigned short h) {
  union { unsigned u; float f; } v; v.u = ((unsigned)h) << 16; return v.f;
}
__device__ __forceinline__ unsigned long long shflxor64(unsigned long long v, int j) {
  unsigned lo = (unsigned)v, hi = (unsigned)(v >> 32);
  lo = (unsigned)__shfl_xor((int)lo, j);
  hi = (unsigned)__shfl_xor((int)hi, j);
  return ((unsigned long long)hi << 32) | lo;
}
__device__ __forceinline__ unsigned long long shfl64(unsigned long long v, int src) {
  unsigned lo = (unsigned)v, hi = (unsigned)(v >> 32);
  lo = (unsigned)__shfl((int)lo, src);
  hi = (unsigned)__shfl((int)hi, src);
  return ((unsigned long long)hi << 32) | lo;
}

// BN param recompute (bit-identical to the old k_finalize), done per consumer block
#define BN_INLINE(S_, Q_, g_, b_, aLds, bLds, CH) \
  if (t < CH) { \
    float s = 0.f, qq = 0.f; \
    for (int c = 0; c < 32; ++c) { s += S_[c*CH + t]; qq += Q_[c*CH + t]; } \
    float mean = s * (1.0f / NPOSF); \
    float var  = qq * (1.0f / NPOSF) - mean*mean; \
    float rs   = 1.0f / sqrtf(var + BNEPS); \
    float a    = g_[t] * rs; \
    aLds[t] = a; bLds[t] = b_[t] - mean*a; \
  }

// ---------- utility kernels ----------
__global__ __launch_bounds__(256) void k_zero(float* p) {
  p[blockIdx.x * 256 + threadIdx.x] = 0.f;
}

// prep: pos2t[b][n] = (x,y,z,x^2+y^2+z^2) (np-pinned rounding) + pos1 passthrough copy
__global__ __launch_bounds__(256) void k_prep(const float* __restrict__ pos2, float4* __restrict__ out,
                                              const float* __restrict__ pos1, float* __restrict__ outP) {
  int i = blockIdx.x * 256 + threadIdx.x;
  int b = i >> 12, n = i & 4095;
  float x = pos2[(b*3 + 0)*NN + n];
  float y = pos2[(b*3 + 1)*NN + n];
  float z = pos2[(b*3 + 2)*NN + n];
  float w = __fadd_rn(__fadd_rn(__fmul_rn(x,x), __fmul_rn(y,y)), __fmul_rn(z,z));
  out[i] = make_float4(x, y, z, w);
  if (i < BB*3*NN/4) {
    *(float4*)(outP + i*4) = *(const float4*)(pos1 + i*4);
  }
}

// [B,64,N] fp32 -> [B,N,64] bf16, both tensors in one launch (z = 2*B)
__global__ __launch_bounds__(256) void k_transposeb2(const float* __restrict__ f2, const float* __restrict__ f1,
                                                     unsigned short* __restrict__ o2, unsigned short* __restrict__ o1) {
  __shared__ float tile[32][33];
  int z = blockIdx.z;
  int b = z & 7;
  const float* in = (z < 8) ? f2 : f1;
  unsigned short* out = (z < 8) ? o2 : o1;
  int n0 = blockIdx.x * 32, c0 = blockIdx.y * 32;
  int tx = threadIdx.x, ty = threadIdx.y;
  #pragma unroll
  for (int i = 0; i < 32; i += 8)
    tile[ty + i][tx] = in[((size_t)(b*CC + c0 + ty + i))*NN + n0 + tx];
  __syncthreads();
  #pragma unroll
  for (int i = 0; i < 32; i += 8)
    out[((size_t)(b*NN + n0 + ty + i))*CC + c0 + tx] = f2bf(tile[tx][ty + i]);
}

// ---------- weight pre-pack: A-fragment order (hi bf16) ----------
__global__ __launch_bounds__(256) void k_wt(const float* __restrict__ W0, const float* __restrict__ W1,
                                            const float* __restrict__ W2, unsigned short* __restrict__ Apk0,
                                            unsigned short* __restrict__ Apk1, unsigned short* __restrict__ Apk2) {
  int i = blockIdx.x * 256 + threadIdx.x;
  if (i < 1280) {            // L0: 4 mt x 5 s x 64 lanes
    int mt = i / 320, r = i % 320, s = r / 64, lane = r % 64;
    int o = mt*16 + (lane & 15), q = lane >> 4, fi = mt*5 + s;
    #pragma unroll
    for (int j = 0; j < 8; ++j) {
      int c = s*32 + q*8 + j;
      float w = 0.f;
      if (c < 131) { int cs = (c < 128) ? (c + 3) : (c - 128); w = W0[o*131 + cs]; }
      Apk0[((size_t)(fi)*64 + lane)*8 + j] = f2bf(w);
    }
  } else if (i < 1792) {     // L1: 4 mt x 2 s
    int k = i - 1280, mt = k / 128, r = k % 128, s = r / 64, lane = r % 64;
    int o = mt*16 + (lane & 15), q = lane >> 4, fi = mt*2 + s;
    #pragma unroll
    for (int j = 0; j < 8; ++j) {
      int c = s*32 + q*8 + j;
      Apk1[((size_t)(fi)*64 + lane)*8 + j] = f2bf(W1[o*64 + c]);
    }
  } else if (i < 2816) {     // L2: 8 mt x 2 s
    int k = i - 1792, mt = k / 128, r = k % 128, s = r / 64, lane = r % 64;
    int o = mt*16 + (lane & 15), q = lane >> 4, fi = mt*2 + s;
    #pragma unroll
    for (int j = 0; j < 8; ++j) {
      int c = s*32 + q*8 + j;
      Apk2[((size_t)(fi)*64 + lane)*8 + j] = f2bf(W2[o*64 + c]);
    }
  }
}

// ---------- KNN pack: A-frags (queries, hi/lo bf16) and B-frags (refs, -2*hi/lo + r2) ----------
__global__ __launch_bounds__(256) void k_packAB(const float* __restrict__ pos1_re,
                                                const float4* __restrict__ pos2t,
                                                unsigned short* __restrict__ ApkQ,
                                                unsigned short* __restrict__ BpkR) {
  int i = blockIdx.x * 256 + threadIdx.x;
  int half = i >> 17;                 // 0: A, 1: B
  int ii = i & 131071;
  int b = ii >> 14, r = ii & 16383;
  int qt = r >> 6, lane = r & 63;
  int li = lane & 15, g = lane >> 4;
  int n = qt*16 + li;
  if (half == 0) {
    float q[3];
    q[0] = pos1_re[(b*3 + 0)*NN + n];
    q[1] = pos1_re[(b*3 + 1)*NN + n];
    q[2] = pos1_re[(b*3 + 2)*NN + n];
    unsigned short qhi[3], qlo[3];
    #pragma unroll
    for (int c = 0; c < 3; ++c) {
      qhi[c] = f2bf(q[c]);
      qlo[c] = f2bf(__fsub_rn(q[c], bf2f(qhi[c])));
    }
    #pragma unroll
    for (int j = 0; j < 8; ++j) {
      int k = g*8 + j;
      unsigned short v = 0;
      if (k < 3)       v = qhi[k];
      else if (k < 6)  v = qhi[k-3];
      else if (k < 9)  v = qlo[k-6];
      else if (k < 11) v = 0x3F80;   // 1.0 bf16
      ApkQ[(((size_t)b*256 + qt)*64 + lane)*8 + j] = v;
    }
  } else {
    float4 rr = pos2t[(size_t)b*NN + n];
    float rc[3] = {rr.x, rr.y, rr.z};
    unsigned short m2hi[3], m2lo[3];
    #pragma unroll
    for (int c = 0; c < 3; ++c) {
      unsigned short rhi = f2bf(rc[c]);
      float rhif = bf2f(rhi);
      m2hi[c] = f2bf(-2.f * rhif);
      unsigned short rlo = f2bf(__fsub_rn(rc[c], rhif));
      m2lo[c] = f2bf(-2.f * bf2f(rlo));
    }
    float r2 = rr.w;
    unsigned short r2hi = f2bf(r2);
    unsigned short r2lo = f2bf(__fsub_rn(r2, bf2f(r2hi)));
    #pragma unroll
    for (int j = 0; j < 8; ++j) {
      int k = g*8 + j;
      unsigned short v = 0;
      if (k < 3)       v = m2hi[k];
      else if (k < 6)  v = m2lo[k-3];
      else if (k < 9)  v = m2hi[k-6];
      else if (k == 9) v = r2hi;
      else if (k == 10)v = r2lo;
      BpkR[(((size_t)b*256 + qt)*64 + lane)*8 + j] = v;
    }
  }
}

// ---------- KNN: MFMA distance filter + exact bitonic select (R6-measured-best config) ----------
__global__ __launch_bounds__(512) void k_knnf(const float* __restrict__ pos1_re,
                                              const float4* __restrict__ pos2t,
                                              const unsigned short* __restrict__ ApkQ,
                                              const unsigned short* __restrict__ BpkR,
                                              unsigned short* __restrict__ idxOut) {
  __shared__ unsigned short lists[16*128];   // 4 KB
  __shared__ unsigned cnts[16];
  __shared__ float smin[16][128];            // 8 KB
  __shared__ float thr[16][2];
  const int t = threadIdx.x, lane = t & 63, wv = t >> 6;
  const int b = blockIdx.y;
  const int qt = blockIdx.x;
  const int li = lane & 15, g = lane >> 4;

  if (t < 16) cnts[t] = 0;

  short8 af = *(const short8*)(ApkQ + (((size_t)b*256 + qt)*64 + lane)*8);
  const unsigned short* bq = BpkR + (size_t)b*256*512 + lane*8;   // tile stride 512 shorts

  const f32x4 zero4 = {0,0,0,0};

  // ---- prepass: per-lane min over 8 sampled tiles in this wave's 32-tile range
  float mn[4] = {3e38f, 3e38f, 3e38f, 3e38f};
  const int off = qt & 3;
  #pragma unroll
  for (int s = 0; s < 8; ++s) {
    short8 bf = *(const short8*)(bq + (size_t)(wv*32 + s*4 + off)*512);
    f32x4 a = MFMA(af, bf, zero4);
    #pragma unroll
    for (int rg = 0; rg < 4; ++rg) mn[rg] = fminf(mn[rg], a[rg]);
  }
  #pragma unroll
  for (int rg = 0; rg < 4; ++rg) smin[g*4 + rg][wv*16 + li] = mn[rg];
  __syncthreads();

  // ---- thresholds: wave wv owns rows wv*2, wv*2+1; rank-10 of 64 pair-combined mins
  #pragma unroll 1
  for (int c = 0; c < 2; ++c) {
    const int rr = wv*2 + c;
    float v = fminf(smin[rr][lane], smin[rr][64 + lane]);
    #pragma unroll
    for (int k = 2; k <= 64; k <<= 1)
      #pragma unroll
      for (int j = k>>1; j > 0; j >>= 1) {
        float p = __shfl_xor(v, j);
        bool keepMin = (((lane & j) == 0) == ((lane & k) == 0));
        float mn_ = fminf(v, p), mx_ = fmaxf(v, p);
        v = keepMin ? mn_ : mx_;
      }
    float t10 = __shfl(v, 9);                 // 10th smallest
    if (lane == 0) {
      const int n = qt*16 + rr;
      float qx = pos1_re[(b*3 + 0)*NN + n];
      float qy = pos1_re[(b*3 + 1)*NN + n];
      float qz = pos1_re[(b*3 + 2)*NN + n];
      float q2 = __fadd_rn(__fadd_rn(__fmul_rn(qx,qx), __fmul_rn(qy,qy)), __fmul_rn(qz,qz));
      float eps2 = __fmaf_rn(1.25e-4f, q2 + 64.f, 6e-4f);   // 2*EPS, generous (validated R2)
      thr[rr][0] = t10;
      thr[rr][1] = t10 + eps2;
    }
  }
  __syncthreads();
  float tsr[4], twr[4];
  #pragma unroll
  for (int rg = 0; rg < 4; ++rg) { tsr[rg] = thr[g*4 + rg][0]; twr[rg] = thr[g*4 + rg][1]; }

  // ---- main scan: this wave's 32 tiles, append survivors
  #pragma unroll 4
  for (int s = 0; s < 32; ++s) {
    const int rt = wv*32 + s;
    short8 bf = *(const short8*)(bq + (size_t)rt*512);
    f32x4 a = MFMA(af, bf, zero4);
    bool any = (a[0] < twr[0]) | (a[1] < twr[1]) | (a[2] < twr[2]) | (a[3] < twr[3]);
    if (__ballot(any)) {
      #pragma unroll
      for (int rg = 0; rg < 4; ++rg) {
        if (a[rg] < twr[rg]) {
          unsigned add = (a[rg] < tsr[rg]) ? 1u : 0x10001u;
          unsigned prev = atomicAdd(&cnts[g*4 + rg], add);
          unsigned pos = prev & 0xffffu;
          if (pos < 128u) lists[((g*4 + rg) << 7) | pos] = (unsigned short)((rt << 4) | li);
        }
      }
    }
  }
  __syncthreads();

  // ---- select: wave wv handles queries wv*2, wv*2+1
  const float4* rp = pos2t + (size_t)b*NN;
  #pragma unroll 1
  for (int c = 0; c < 2; ++c) {
    const int qi = wv*2 + c;
    const int n = qt*16 + qi;
    unsigned cw = cnts[qi];
    unsigned cnt = cw & 0xffffu;
    int c0q = (int)cnt - (int)(cw >> 16);

    const float qx = pos1_re[(b*3 + 0)*NN + n];
    const float qy = pos1_re[(b*3 + 1)*NN + n];
    const float qz = pos1_re[(b*3 + 2)*NN + n];
    const float q2 = __fadd_rn(__fadd_rn(__fmul_rn(qx,qx), __fmul_rn(qy,qy)), __fmul_rn(qz,qz));

    if (c0q >= 16 && cnt <= 128u) {
      const unsigned short* lst = &lists[qi << 7];
      unsigned long long key = ~0ull;
      if (lane < (int)cnt) {
        int ix = lst[lane];
        float4 r = rp[ix];
        float dot = __fadd_rn(__fadd_rn(__fmul_rn(qx,r.x), __fmul_rn(qy,r.y)), __fmul_rn(qz,r.z));
        float d   = __fsub_rn(__fadd_rn(q2, r.w), __fmul_rn(2.0f, dot));
        unsigned du = __float_as_uint(d);
        du ^= (du >> 31) ? 0xFFFFFFFFu : 0x80000000u;
        key = ((unsigned long long)du << 16) | (unsigned)ix;
      }
      #pragma unroll
      for (int k = 2; k <= 64; k <<= 1)
        #pragma unroll
        for (int j = k>>1; j > 0; j >>= 1) {
          unsigned long long p = shflxor64(key, j);
          bool keepMin = (((lane & j) == 0) == ((lane & k) == 0));
          unsigned long long mnk = key < p ? key : p, mxk = key < p ? p : key;
          key = keepMin ? mnk : mxk;
        }
      if (cnt > 64u) {
        unsigned long long k2 = ~0ull;
        if (lane + 64 < (int)cnt) {
          int ix = lst[64 + lane];
          float4 r = rp[ix];
          float dot = __fadd_rn(__fadd_rn(__fmul_rn(qx,r.x), __fmul_rn(qy,r.y)), __fmul_rn(qz,r.z));
          float d   = __fsub_rn(__fadd_rn(q2, r.w), __fmul_rn(2.0f, dot));
          unsigned du = __float_as_uint(d);
          du ^= (du >> 31) ? 0xFFFFFFFFu : 0x80000000u;
          k2 = ((unsigned long long)du << 16) | (unsigned)ix;
        }
        #pragma unroll
        for (int k = 2; k <= 64; k <<= 1)
          #pragma unroll
          for (int j = k>>1; j > 0; j >>= 1) {
            unsigned long long p = shflxor64(k2, j);
            bool keepMin = (((lane & j) == 0) == ((lane & k) == 0));
            unsigned long long mnk = k2 < p ? k2 : p, mxk = k2 < p ? p : k2;
            k2 = keepMin ? mnk : mxk;
          }
        unsigned long long pb = shfl64(k2, (15 - lane) & 63);
        key = key < pb ? key : pb;
      }
      if (lane < 16) idxOut[((size_t)(b*NN + n))*KK + lane] = (unsigned short)(key & 0xffffull);
    } else {
      // fallback: verbatim validated full scan
      unsigned bd  = 0xFFFFFFFFu;
      unsigned bix = 0u;
      unsigned tau = 0xFFFFFFFFu;
      for (int it = 0; it < 64; ++it) {
        float4 r = rp[it*64 + lane];
        float dot = __fadd_rn(__fadd_rn(__fmul_rn(qx,r.x), __fmul_rn(qy,r.y)), __fmul_rn(qz,r.z));
        float d   = __fsub_rn(__fadd_rn(q2, r.w), __fmul_rn(2.0f, dot));
        unsigned du = __float_as_uint(d);
        du ^= (du >> 31) ? 0xFFFFFFFFu : 0x80000000u;
        unsigned long long mask = __ballot(du < tau);
        while (mask) {
          const int l = __ffsll((unsigned long long)mask) - 1;
          mask &= (mask - 1);
          const unsigned sd = (unsigned)__builtin_amdgcn_readlane((int)du, l);
          if (sd >= tau) continue;
          const unsigned sidx = (unsigned)(it*64 + l);
          int m = (bd > sd) ? 1 : 0;
          int pm = __builtin_amdgcn_update_dpp(0, m, 0x111, 0xF, 0xF, true);
          unsigned sb = (unsigned)__builtin_amdgcn_update_dpp(0, (int)bd,  0x111, 0xF, 0xF, true);
          unsigned si = (unsigned)__builtin_amdgcn_update_dpp(0, (int)bix, 0x111, 0xF, 0xF, true);
          if (m) { bd = pm ? sb : sd; bix = pm ? si : sidx; }
          tau = (unsigned)__builtin_amdgcn_readlane((int)bd, 15);
        }
      }
      if (lane < 16) idxOut[((size_t)(b*NN + n))*KK + lane] = (unsigned short)bix;
    }
  }
}

// ---------- wave-level deferred stat reduce (once per wave) ----------
#define WAVE_STATS(NMT) { \
  _Pragma("unroll") \
  for (int mt = 0; mt < NMT; ++mt) { \
    _Pragma("unroll") \
    for (int rg = 0; rg < 4; ++rg) { \
      float s_ = sacc[mt][rg], q_ = sqacc[mt][rg]; \
      s_ += __shfl_xor(s_,1); s_ += __shfl_xor(s_,2); s_ += __shfl_xor(s_,4); s_ += __shfl_xor(s_,8); \
      q_ += __shfl_xor(q_,1); q_ += __shfl_xor(q_,2); q_ += __shfl_xor(q_,4); q_ += __shfl_xor(q_,8); \
      if (cl == 0) { atomicAdd(&sS[mt*16 + q*4 + rg], s_); atomicAdd(&sQ[mt*16 + q*4 + rg], q_); } \
    } \
  } }

// ---------- layer 0: gather -> MFMA, reg weights; R11: 1D grid, b = blockIdx&7 (XCD-local gather reuse) ----------
__global__ __launch_bounds__(256) void k_layer0(
    const unsigned short* __restrict__ nidx, const float4* __restrict__ pos2t,
    const float* __restrict__ pos1, const unsigned short* __restrict__ f2b,
    const unsigned short* __restrict__ f1b, const unsigned short* __restrict__ Apk0,
    unsigned short* __restrict__ Y0, float* __restrict__ gS, float* __restrict__ gQ) {
  __shared__ float sS[64], sQ[64];
  const int t = threadIdx.x, lane = t & 63, wv = t >> 6;
  // XCD swizzle: consecutive block IDs round-robin across the 8 XCDs; put all
  // blocks of batch b on XCD b so f2b[b] (4 MB) stays resident in that XCD's L2.
  const int b = blockIdx.x & 7, xt = blockIdx.x >> 3;
  const int n0 = xt*32 + wv*8;
  const int cl = lane & 15, q = lane >> 4;

  short8 Wr[20];
  #pragma unroll
  for (int f = 0; f < 20; ++f) Wr[f] = *(const short8*)(Apk0 + ((size_t)f*64 + lane)*8);
  if (t < 64) { sS[t] = 0.f; sQ[t] = 0.f; }
  __syncthreads();

  f32x4 sacc[4]  = {{0,0,0,0},{0,0,0,0},{0,0,0,0},{0,0,0,0}};
  f32x4 sqacc[4] = {{0,0,0,0},{0,0,0,0},{0,0,0,0},{0,0,0,0}};

  #pragma unroll 1
  for (int p = 0; p < 8; ++p) {
    const int n = n0 + p;
    const int m = (int)nidx[((size_t)(b*NN + n))*KK + cl];
    const unsigned short* f2r = f2b + ((size_t)(b*NN + m))*64;
    const unsigned short* f1r = f1b + ((size_t)(b*NN + n))*64;
    short8 x0 = *(const short8*)(f2r + q*8);
    short8 x1 = *(const short8*)(f2r + 32 + q*8);
    short8 x2 = *(const short8*)(f1r + q*8);
    short8 x3 = *(const short8*)(f1r + 32 + q*8);
    short8 x4 = {0,0,0,0,0,0,0,0};
    if (q == 0) {
      float4 pp = pos2t[(size_t)b*NN + m];
      float px = pos1[(b*3 + 0)*NN + n];
      float py = pos1[(b*3 + 1)*NN + n];
      float pz = pos1[(b*3 + 2)*NN + n];
      x4[0] = (short)f2bf(pp.x - px);
      x4[1] = (short)f2bf(pp.y - py);
      x4[2] = (short)f2bf(pp.z - pz);
    }
    f32x4 acc[4] = {{0,0,0,0},{0,0,0,0},{0,0,0,0},{0,0,0,0}};
    #pragma unroll
    for (int mt = 0; mt < 4; ++mt) {
      acc[mt] = MFMA(Wr[mt*5 + 0], x0, acc[mt]);
      acc[mt] = MFMA(Wr[mt*5 + 1], x1, acc[mt]);
      acc[mt] = MFMA(Wr[mt*5 + 2], x2, acc[mt]);
      acc[mt] = MFMA(Wr[mt*5 + 3], x3, acc[mt]);
      acc[mt] = MFMA(Wr[mt*5 + 4], x4, acc[mt]);
    }
    unsigned short* yr = Y0 + (((size_t)(b*NN + n))*KK + cl)*64;
    #pragma unroll
    for (int mt = 0; mt < 4; ++mt) {
      sacc[mt]  += acc[mt];
      sqacc[mt] += acc[mt]*acc[mt];
      ushort4 pk; pk.x = f2bf(acc[mt][0]); pk.y = f2bf(acc[mt][1]);
      pk.z = f2bf(acc[mt][2]); pk.w = f2bf(acc[mt][3]);
      *(ushort4*)(yr + mt*16 + q*4) = pk;
    }
  }
  WAVE_STATS(4)
  __syncthreads();
  const int slot = xt & 31;
  if (t < 64) { atomicAdd(&gS[slot*64 + t], sS[t]); atomicAdd(&gQ[slot*64 + t], sQ[t]); }
}

// ---------- layer 1: inline-bn0(S0,Q0)+relu(Y0) -> MFMA(64x64), reg weights ----------
__global__ __launch_bounds__(256) void k_layer1(
    const unsigned short* __restrict__ Y0, const float* __restrict__ S0, const float* __restrict__ Q0,
    const float* __restrict__ g0, const float* __restrict__ b0,
    const unsigned short* __restrict__ Apk1, unsigned short* __restrict__ Y1,
    float* __restrict__ gS, float* __restrict__ gQ) {
  __shared__ float sS[64], sQ[64];
  __shared__ float aL[64], bL[64];
  const int t = threadIdx.x, lane = t & 63, wv = t >> 6;
  const int b = blockIdx.y, n0 = blockIdx.x*32 + wv*8;
  const int cl = lane & 15, q = lane >> 4;

  short8 Wr[8];
  #pragma unroll
  for (int f = 0; f < 8; ++f) Wr[f] = *(const short8*)(Apk1 + ((size_t)f*64 + lane)*8);
  BN_INLINE(S0, Q0, g0, b0, aL, bL, 64)
  if (t >= 64 && t < 128) { sS[t-64] = 0.f; sQ[t-64] = 0.f; }
  __syncthreads();

  float ar[16], br[16];
  #pragma unroll
  for (int s = 0; s < 2; ++s)
    #pragma unroll
    for (int j = 0; j < 8; ++j) { int c = s*32 + q*8 + j; ar[s*8+j] = aL[c]; br[s*8+j] = bL[c]; }

  f32x4 sacc[4]  = {{0,0,0,0},{0,0,0,0},{0,0,0,0},{0,0,0,0}};
  f32x4 sqacc[4] = {{0,0,0,0},{0,0,0,0},{0,0,0,0},{0,0,0,0}};

  #pragma unroll 1
  for (int p = 0; p < 8; ++p) {
    const int n = n0 + p;
    const unsigned short* yr = Y0 + (((size_t)(b*NN + n))*KK + cl)*64;
    short8 u0 = *(const short8*)(yr + q*8);
    short8 u1 = *(const short8*)(yr + 32 + q*8);
    short8 x0, x1;
    #pragma unroll
    for (int j = 0; j < 8; ++j) {
      x0[j] = (short)f2bf(fmaxf(bf2f((unsigned short)u0[j])*ar[j]   + br[j],   0.f));
      x1[j] = (short)f2bf(fmaxf(bf2f((unsigned short)u1[j])*ar[8+j] + br[8+j], 0.f));
    }
    f32x4 acc[4] = {{0,0,0,0},{0,0,0,0},{0,0,0,0},{0,0,0,0}};
    #pragma unroll
    for (int mt = 0; mt < 4; ++mt) {
      acc[mt] = MFMA(Wr[mt*2 + 0], x0, acc[mt]);
      acc[mt] = MFMA(Wr[mt*2 + 1], x1, acc[mt]);
    }
    unsigned short* yw = Y1 + (((size_t)(b*NN + n))*KK + cl)*64;
    #pragma unroll
    for (int mt = 0; mt < 4; ++mt) {
      sacc[mt]  += acc[mt];
      sqacc[mt] += acc[mt]*acc[mt];
      ushort4 pk; pk.x = f2bf(acc[mt][0]); pk.y = f2bf(acc[mt][1]);
      pk.z = f2bf(acc[mt][2]); pk.w = f2bf(acc[mt][3]);
      *(ushort4*)(yw + mt*16 + q*4) = pk;
    }
  }
  WAVE_STATS(4)
  __syncthreads();
  const int slot = blockIdx.x & 31;
  if (t < 64) { atomicAdd(&gS[slot*64 + t], sS[t]); atomicAdd(&gQ[slot*64 + t], sQ[t]); }
}

// ---------- layer 2 stats + extrema: inline-bn1(S1,Q1)+relu(Y1) -> MFMA(x,W) ----------
__global__ __launch_bounds__(256) void k_l2stats(
    const unsigned short* __restrict__ Y1, const float* __restrict__ S1, const float* __restrict__ Q1,
    const float* __restrict__ g1, const float* __restrict__ b1,
    const unsigned short* __restrict__ Apk2, float2* __restrict__ Ypk,
    float* __restrict__ gS, float* __restrict__ gQ) {
  __shared__ float sS[128], sQ[128];
  __shared__ float aL[64], bL[64];
  const int t = threadIdx.x, lane = t & 63, wv = t >> 6;
  const int b = blockIdx.y, n0 = blockIdx.x*32 + wv*8;
  const int cl = lane & 15, q = lane >> 4;

  short8 Wr[16];
  #pragma unroll
  for (int f = 0; f < 16; ++f) Wr[f] = *(const short8*)(Apk2 + ((size_t)f*64 + lane)*8);
  BN_INLINE(S1, Q1, g1, b1, aL, bL, 64)
  if (t >= 64 && t < 192) { sS[t-64] = 0.f; sQ[t-64] = 0.f; }
  __syncthreads();

  float ar[16], br[16];
  #pragma unroll
  for (int s = 0; s < 2; ++s)
    #pragma unroll
    for (int j = 0; j < 8; ++j) { int c = s*32 + q*8 + j; ar[s*8+j] = aL[c]; br[s*8+j] = bL[c]; }

  float ssum[8] = {0,0,0,0,0,0,0,0};
  float sqsum[8] = {0,0,0,0,0,0,0,0};

  #pragma unroll 1
  for (int p = 0; p < 8; ++p) {
    const int n = n0 + p;
    const unsigned short* yr = Y1 + (((size_t)(b*NN + n))*KK + cl)*64;
    short8 u0 = *(const short8*)(yr + q*8);
    short8 u1 = *(const short8*)(yr + 32 + q*8);
    short8 x0, x1;
    #pragma unroll
    for (int j = 0; j < 8; ++j) {
      x0[j] = (short)f2bf(fmaxf(bf2f((unsigned short)u0[j])*ar[j]   + br[j],   0.f));
      x1[j] = (short)f2bf(fmaxf(bf2f((unsigned short)u1[j])*ar[8+j] + br[8+j], 0.f));
    }
    float2* yw = Ypk + ((size_t)(b*NN + n))*H2;
    #pragma unroll
    for (int mt = 0; mt < 8; ++mt) {
      f32x4 acc = {0,0,0,0};
      acc = MFMA(x0, Wr[mt*2 + 0], acc);     // swapped: D[k][ch]
      acc = MFMA(x1, Wr[mt*2 + 1], acc);
      ssum[mt]  += (acc[0] + acc[1]) + (acc[2] + acc[3]);
      sqsum[mt] += acc[0]*acc[0] + acc[1]*acc[1] + acc[2]*acc[2] + acc[3]*acc[3];
      float mx = fmaxf(fmaxf(acc[0], acc[1]), fmaxf(acc[2], acc[3]));
      float mn = fminf(fminf(acc[0], acc[1]), fminf(acc[2], acc[3]));
      mx = fmaxf(mx, __shfl_xor(mx, 16)); mx = fmaxf(mx, __shfl_xor(mx, 32));
      mn = fminf(mn, __shfl_xor(mn, 16)); mn = fminf(mn, __shfl_xor(mn, 32));
      if (lane < 16) yw[mt*16 + lane] = make_float2(mx, mn);
    }
  }
  #pragma unroll
  for (int mt = 0; mt < 8; ++mt) {
    float s_ = ssum[mt], q_ = sqsum[mt];
    s_ += __shfl_xor(s_, 16); s_ += __shfl_xor(s_, 32);
    q_ += __shfl_xor(q_, 16); q_ += __shfl_xor(q_, 32);
    if (lane < 16) { atomicAdd(&sS[mt*16 + cl], s_); atomicAdd(&sQ[mt*16 + cl], q_); }
  }
  __syncthreads();
  const int slot = blockIdx.x & 31;
  if (t < 128) { atomicAdd(&gS[slot*128 + t], sS[t]); atomicAdd(&gQ[slot*128 + t], sQ[t]); }
}

// ---------- final: inline-bn2(S2,Q2) + relu + (k-max via stored extrema) -> out ----------
__global__ __launch_bounds__(256) void k_bnmax(
    const float2* __restrict__ Ypk, const float* __restrict__ S2, const float* __restrict__ Q2,
    const float* __restrict__ g2, const float* __restrict__ b2,
    float* __restrict__ outF) {
  __shared__ float a2s[128], b2s[128];
  __shared__ float oBuf[32*128];   // 16 KB [np][ch]
  const int t = threadIdx.x;
  const int b = blockIdx.y, nb = blockIdx.x*32;
  BN_INLINE(S2, Q2, g2, b2, a2s, b2s, 128)
  __syncthreads();

  const float2* src = Ypk + ((size_t)(b*NN + nb))*H2;
  #pragma unroll
  for (int e = 0; e < 16; ++e) {
    int i = e*256 + t;
    float2 v = src[i];
    int ch = i & 127;
    float a = a2s[ch];
    float sel = (a >= 0.f) ? v.x : v.y;
    oBuf[i] = fmaxf(sel*a + b2s[ch], 0.f);
  }
  __syncthreads();
  {
    const int ch = t & 127, npb = (t >> 7) * 16;
    #pragma unroll
    for (int g = 0; g < 4; ++g) {
      float4 v = make_float4(oBuf[(npb + g*4 + 0)*128 + ch],
                             oBuf[(npb + g*4 + 1)*128 + ch],
                             oBuf[(npb + g*4 + 2)*128 + ch],
                             oBuf[(npb + g*4 + 3)*128 + ch]);
      *(float4*)(outF + ((size_t)(b*H2 + ch))*NN + nb + npb + g*4) = v;
    }
  }
}

// ---------- launch ----------
extern "C" void kernel_launch(void* const* d_in, const int* in_sizes, int n_in,
                              void* d_out, int out_size, void* d_ws, size_t ws_size,
                              hipStream_t stream) {
  const float* pos1    = (const float*)d_in[0];
  const float* pos1_re = (const float*)d_in[1];
  const float* pos2    = (const float*)d_in[2];
  const float* f1      = (const float*)d_in[3];
  const float* f2      = (const float*)d_in[4];
  const float* W0 = (const float*)d_in[6];
  const float* g0 = (const float*)d_in[7];
  const float* b0 = (const float*)d_in[8];
  const float* W1 = (const float*)d_in[9];
  const float* g1 = (const float*)d_in[10];
  const float* b1 = (const float*)d_in[11];
  const float* W2 = (const float*)d_in[12];
  const float* g2 = (const float*)d_in[13];
  const float* b2 = (const float*)d_in[14];
  float* out = (float*)d_out;

  // workspace layout (bytes)
  char* ws = (char*)d_ws;
  float* stats = (float*)ws;                 // 65536 B
  float* S0 = stats;         float* Q0 = stats + 2048;
  float* S1 = stats + 4096;  float* Q1 = stats + 6144;
  float* S2 = stats + 8192;  float* Q2 = stats + 12288;
  unsigned short* Apk0 = (unsigned short*)(ws + 67584);    // 20480 B (hi only used)
  unsigned short* Apk1 = (unsigned short*)(ws + 108544);   // 8192 B used
  unsigned short* Apk2 = (unsigned short*)(ws + 124928);   // 16384 B used
  unsigned short* idxb = (unsigned short*)(ws + 157696);   // 1 MB
  float4* pos2t        = (float4*)(ws + 1206272);          // 512 KB
  unsigned short* f2b  = (unsigned short*)(ws + 1730560);  // 4 MB
  unsigned short* f1b  = (unsigned short*)(ws + 5924864);  // 4 MB
  unsigned short* Y0   = (unsigned short*)(ws + 10119168); // 64 MB
  unsigned short* Y1   = (unsigned short*)(ws + 77228032); // 64 MB -> 144336896
  // KNN pack buffers alias the Y0 region (dead until k_layer0 runs, stream-ordered)
  unsigned short* ApkQ = (unsigned short*)(ws + 10119168);            // 2 MB
  unsigned short* BpkR = (unsigned short*)(ws + 10119168 + 2097152);  // 2 MB
  // y2 extrema pairs alias the Y0 region too (Y0 dead after k_layer1): 32 MB
  float2* Ypk          = (float2*)(ws + 10119168);
  if (ws_size < 144336896u) return;

  k_zero<<<dim3(64), 256, 0, stream>>>(stats);
  k_wt<<<dim3(11), 256, 0, stream>>>(W0, W1, W2, Apk0, Apk1, Apk2);
  k_prep<<<dim3(BB*NN/256), 256, 0, stream>>>(pos2, pos2t, pos1, out);
  k_packAB<<<dim3(1024), 256, 0, stream>>>(pos1_re, pos2t, ApkQ, BpkR);
  k_transposeb2<<<dim3(NN/32, CC/32, 2*BB), dim3(32, 8), 0, stream>>>(f2, f1, f2b, f1b);
  k_knnf<<<dim3(256, BB), 512, 0, stream>>>(pos1_re, pos2t, ApkQ, BpkR, idxb);

  k_layer0<<<dim3(NN/32*BB), 256, 0, stream>>>(idxb, pos2t, pos1, f2b, f1b, Apk0, Y0, S0, Q0);
  k_layer1<<<dim3(NN/32, BB), 256, 0, stream>>>(Y0, S0, Q0, g0, b0, Apk1, Y1, S1, Q1);
  k_l2stats<<<dim3(NN/32, BB), 256, 0, stream>>>(Y1, S1, Q1, g1, b1, Apk2, Ypk, S2, Q2);
  k_bnmax<<<dim3(NN/32, BB), 256, 0, stream>>>(Ypk, S2, Q2, g2, b2, out + (size_t)BB*3*NN);
}

// Round 12
// 310.576 us; speedup vs baseline: 1.0248x; 1.0056x over previous
//
#include <hip/hip_runtime.h>
#include <hip/hip_bf16.h>
#include <cstdint>
#include <cstddef>

#define BB   8
#define NN   4096
#define CC   64
#define KK   16
#define H2   128
#define NPOSF 524288.0f
#define BNEPS 1e-5f

typedef __attribute__((ext_vector_type(8))) short  short8;
typedef __attribute__((ext_vector_type(4))) float  f32x4;

#define MFMA(a,b,c) __builtin_amdgcn_mfma_f32_16x16x32_bf16(a, b, c, 0, 0, 0)

// ---------- helpers ----------
__device__ __forceinline__ unsigned short f2bf(float x) {
  union { float f; unsigned u; } v; v.f = x;
  unsigned u = v.u;
  return (unsigned short)((u + 0x7fffu + ((u >> 16) & 1u)) >> 16);
}
__device__ __forceinline__ float bf2f(unsigned short h) {
  union { unsigned u; float f; } v; v.u = ((unsigned)h) << 16; return v.f;
}
__device__ __forceinline__ unsigned long long shflxor64(unsigned long long v, int j) {
  unsigned lo = (unsigned)v, hi = (unsigned)(v >> 32);
  lo = (unsigned)__shfl_xor((int)lo, j);
  hi = (unsigned)__shfl_xor((int)hi, j);
  return ((unsigned long long)hi << 32) | lo;
}
__device__ __forceinline__ unsigned long long shfl64(unsigned long long v, int src) {
  unsigned lo = (unsigned)v, hi = (unsigned)(v >> 32);
  lo = (unsigned)__shfl((int)lo, src);
  hi = (unsigned)__shfl((int)hi, src);
  return ((unsigned long long)hi << 32) | lo;
}

// BN param recompute (bit-identical to the old k_finalize), done per consumer block
#define BN_INLINE(S_, Q_, g_, b_, aLds, bLds, CH) \
  if (t < CH) { \
    float s = 0.f, qq = 0.f; \
    for (int c = 0; c < 32; ++c) { s += S_[c*CH + t]; qq += Q_[c*CH + t]; } \
    float mean = s * (1.0f / NPOSF); \
    float var  = qq * (1.0f / NPOSF) - mean*mean; \
    float rs   = 1.0f / sqrtf(var + BNEPS); \
    float a    = g_[t] * rs; \
    aLds[t] = a; bLds[t] = b_[t] - mean*a; \
  }

// ---------- prep: pos2t + pos1 passthrough + stats zero (k_zero folded in) ----------
__global__ __launch_bounds__(256) void k_prep(const float* __restrict__ pos2, float4* __restrict__ out,
                                              const float* __restrict__ pos1, float* __restrict__ outP,
                                              float* __restrict__ stats) {
  int i = blockIdx.x * 256 + threadIdx.x;
  int b = i >> 12, n = i & 4095;
  float x = pos2[(b*3 + 0)*NN + n];
  float y = pos2[(b*3 + 1)*NN + n];
  float z = pos2[(b*3 + 2)*NN + n];
  float w = __fadd_rn(__fadd_rn(__fmul_rn(x,x), __fmul_rn(y,y)), __fmul_rn(z,z));
  out[i] = make_float4(x, y, z, w);
  if (i < BB*3*NN/4) {
    *(float4*)(outP + i*4) = *(const float4*)(pos1 + i*4);
  }
  if (i < 16384) stats[i] = 0.f;
}

// [B,64,N] fp32 -> [B,N,64] bf16, both tensors in one launch (z = 2*B)
__global__ __launch_bounds__(256) void k_transposeb2(const float* __restrict__ f2, const float* __restrict__ f1,
                                                     unsigned short* __restrict__ o2, unsigned short* __restrict__ o1) {
  __shared__ float tile[32][33];
  int z = blockIdx.z;
  int b = z & 7;
  const float* in = (z < 8) ? f2 : f1;
  unsigned short* out = (z < 8) ? o2 : o1;
  int n0 = blockIdx.x * 32, c0 = blockIdx.y * 32;
  int tx = threadIdx.x, ty = threadIdx.y;
  #pragma unroll
  for (int i = 0; i < 32; i += 8)
    tile[ty + i][tx] = in[((size_t)(b*CC + c0 + ty + i))*NN + n0 + tx];
  __syncthreads();
  #pragma unroll
  for (int i = 0; i < 32; i += 8)
    out[((size_t)(b*NN + n0 + ty + i))*CC + c0 + tx] = f2bf(tile[tx][ty + i]);
}

// ---------- weight pre-pack: A-fragment order (hi bf16) ----------
__global__ __launch_bounds__(256) void k_wt(const float* __restrict__ W0, const float* __restrict__ W1,
                                            const float* __restrict__ W2, unsigned short* __restrict__ Apk0,
                                            unsigned short* __restrict__ Apk1, unsigned short* __restrict__ Apk2) {
  int i = blockIdx.x * 256 + threadIdx.x;
  if (i < 1280) {            // L0: 4 mt x 5 s x 64 lanes
    int mt = i / 320, r = i % 320, s = r / 64, lane = r % 64;
    int o = mt*16 + (lane & 15), q = lane >> 4, fi = mt*5 + s;
    #pragma unroll
    for (int j = 0; j < 8; ++j) {
      int c = s*32 + q*8 + j;
      float w = 0.f;
      if (c < 131) { int cs = (c < 128) ? (c + 3) : (c - 128); w = W0[o*131 + cs]; }
      Apk0[((size_t)(fi)*64 + lane)*8 + j] = f2bf(w);
    }
  } else if (i < 1792) {     // L1: 4 mt x 2 s
    int k = i - 1280, mt = k / 128, r = k % 128, s = r / 64, lane = r % 64;
    int o = mt*16 + (lane & 15), q = lane >> 4, fi = mt*2 + s;
    #pragma unroll
    for (int j = 0; j < 8; ++j) {
      int c = s*32 + q*8 + j;
      Apk1[((size_t)(fi)*64 + lane)*8 + j] = f2bf(W1[o*64 + c]);
    }
  } else if (i < 2816) {     // L2: 8 mt x 2 s
    int k = i - 1792, mt = k / 128, r = k % 128, s = r / 64, lane = r % 64;
    int o = mt*16 + (lane & 15), q = lane >> 4, fi = mt*2 + s;
    #pragma unroll
    for (int j = 0; j < 8; ++j) {
      int c = s*32 + q*8 + j;
      Apk2[((size_t)(fi)*64 + lane)*8 + j] = f2bf(W2[o*64 + c]);
    }
  }
}

// ---------- KNN pack: A-frags (queries, hi/lo bf16) and B-frags (refs, -2*hi/lo + r2) ----------
__global__ __launch_bounds__(256) void k_packAB(const float* __restrict__ pos1_re,
                                                const float4* __restrict__ pos2t,
                                                unsigned short* __restrict__ ApkQ,
                                                unsigned short* __restrict__ BpkR) {
  int i = blockIdx.x * 256 + threadIdx.x;
  int half = i >> 17;                 // 0: A, 1: B
  int ii = i & 131071;
  int b = ii >> 14, r = ii & 16383;
  int qt = r >> 6, lane = r & 63;
  int li = lane & 15, g = lane >> 4;
  int n = qt*16 + li;
  if (half == 0) {
    float q[3];
    q[0] = pos1_re[(b*3 + 0)*NN + n];
    q[1] = pos1_re[(b*3 + 1)*NN + n];
    q[2] = pos1_re[(b*3 + 2)*NN + n];
    unsigned short qhi[3], qlo[3];
    #pragma unroll
    for (int c = 0; c < 3; ++c) {
      qhi[c] = f2bf(q[c]);
      qlo[c] = f2bf(__fsub_rn(q[c], bf2f(qhi[c])));
    }
    #pragma unroll
    for (int j = 0; j < 8; ++j) {
      int k = g*8 + j;
      unsigned short v = 0;
      if (k < 3)       v = qhi[k];
      else if (k < 6)  v = qhi[k-3];
      else if (k < 9)  v = qlo[k-6];
      else if (k < 11) v = 0x3F80;   // 1.0 bf16
      ApkQ[(((size_t)b*256 + qt)*64 + lane)*8 + j] = v;
    }
  } else {
    float4 rr = pos2t[(size_t)b*NN + n];
    float rc[3] = {rr.x, rr.y, rr.z};
    unsigned short m2hi[3], m2lo[3];
    #pragma unroll
    for (int c = 0; c < 3; ++c) {
      unsigned short rhi = f2bf(rc[c]);
      float rhif = bf2f(rhi);
      m2hi[c] = f2bf(-2.f * rhif);
      unsigned short rlo = f2bf(__fsub_rn(rc[c], rhif));
      m2lo[c] = f2bf(-2.f * bf2f(rlo));
    }
    float r2 = rr.w;
    unsigned short r2hi = f2bf(r2);
    unsigned short r2lo = f2bf(__fsub_rn(r2, bf2f(r2hi)));
    #pragma unroll
    for (int j = 0; j < 8; ++j) {
      int k = g*8 + j;
      unsigned short v = 0;
      if (k < 3)       v = m2hi[k];
      else if (k < 6)  v = m2lo[k-3];
      else if (k < 9)  v = m2hi[k-6];
      else if (k == 9) v = r2hi;
      else if (k == 10)v = r2lo;
      BpkR[(((size_t)b*256 + qt)*64 + lane)*8 + j] = v;
    }
  }
}

// ---------- KNN: MFMA distance filter + exact bitonic select ----------
// R12: R6 config + __launch_bounds__(512,8) (request 32 waves/CU) + scan unroll 8.
__global__ __launch_bounds__(512, 8) void k_knnf(const float* __restrict__ pos1_re,
                                                 const float4* __restrict__ pos2t,
                                                 const unsigned short* __restrict__ ApkQ,
                                                 const unsigned short* __restrict__ BpkR,
                                                 unsigned short* __restrict__ idxOut) {
  __shared__ unsigned short lists[16*128];   // 4 KB
  __shared__ unsigned cnts[16];
  __shared__ float smin[16][128];            // 8 KB
  __shared__ float thr[16][2];
  const int t = threadIdx.x, lane = t & 63, wv = t >> 6;
  const int b = blockIdx.y;
  const int qt = blockIdx.x;
  const int li = lane & 15, g = lane >> 4;

  if (t < 16) cnts[t] = 0;

  short8 af = *(const short8*)(ApkQ + (((size_t)b*256 + qt)*64 + lane)*8);
  const unsigned short* bq = BpkR + (size_t)b*256*512 + lane*8;   // tile stride 512 shorts

  const f32x4 zero4 = {0,0,0,0};

  // ---- prepass: per-lane min over 8 sampled tiles in this wave's 32-tile range
  float mn[4] = {3e38f, 3e38f, 3e38f, 3e38f};
  const int off = qt & 3;
  #pragma unroll
  for (int s = 0; s < 8; ++s) {
    short8 bf = *(const short8*)(bq + (size_t)(wv*32 + s*4 + off)*512);
    f32x4 a = MFMA(af, bf, zero4);
    #pragma unroll
    for (int rg = 0; rg < 4; ++rg) mn[rg] = fminf(mn[rg], a[rg]);
  }
  #pragma unroll
  for (int rg = 0; rg < 4; ++rg) smin[g*4 + rg][wv*16 + li] = mn[rg];
  __syncthreads();

  // ---- thresholds: wave wv owns rows wv*2, wv*2+1; rank-10 of 64 pair-combined mins
  #pragma unroll 1
  for (int c = 0; c < 2; ++c) {
    const int rr = wv*2 + c;
    float v = fminf(smin[rr][lane], smin[rr][64 + lane]);
    #pragma unroll
    for (int k = 2; k <= 64; k <<= 1)
      #pragma unroll
      for (int j = k>>1; j > 0; j >>= 1) {
        float p = __shfl_xor(v, j);
        bool keepMin = (((lane & j) == 0) == ((lane & k) == 0));
        float mn_ = fminf(v, p), mx_ = fmaxf(v, p);
        v = keepMin ? mn_ : mx_;
      }
    float t10 = __shfl(v, 9);                 // 10th smallest
    if (lane == 0) {
      const int n = qt*16 + rr;
      float qx = pos1_re[(b*3 + 0)*NN + n];
      float qy = pos1_re[(b*3 + 1)*NN + n];
      float qz = pos1_re[(b*3 + 2)*NN + n];
      float q2 = __fadd_rn(__fadd_rn(__fmul_rn(qx,qx), __fmul_rn(qy,qy)), __fmul_rn(qz,qz));
      float eps2 = __fmaf_rn(1.25e-4f, q2 + 64.f, 6e-4f);   // 2*EPS, generous (validated R2)
      thr[rr][0] = t10;
      thr[rr][1] = t10 + eps2;
    }
  }
  __syncthreads();
  float tsr[4], twr[4];
  #pragma unroll
  for (int rg = 0; rg < 4; ++rg) { tsr[rg] = thr[g*4 + rg][0]; twr[rg] = thr[g*4 + rg][1]; }

  // ---- main scan: this wave's 32 tiles, append survivors (8 loads in flight)
  #pragma unroll 8
  for (int s = 0; s < 32; ++s) {
    const int rt = wv*32 + s;
    short8 bf = *(const short8*)(bq + (size_t)rt*512);
    f32x4 a = MFMA(af, bf, zero4);
    bool any = (a[0] < twr[0]) | (a[1] < twr[1]) | (a[2] < twr[2]) | (a[3] < twr[3]);
    if (__ballot(any)) {
      #pragma unroll
      for (int rg = 0; rg < 4; ++rg) {
        if (a[rg] < twr[rg]) {
          unsigned add = (a[rg] < tsr[rg]) ? 1u : 0x10001u;
          unsigned prev = atomicAdd(&cnts[g*4 + rg], add);
          unsigned pos = prev & 0xffffu;
          if (pos < 128u) lists[((g*4 + rg) << 7) | pos] = (unsigned short)((rt << 4) | li);
        }
      }
    }
  }
  __syncthreads();

  // ---- select: wave wv handles queries wv*2, wv*2+1
  const float4* rp = pos2t + (size_t)b*NN;
  #pragma unroll 1
  for (int c = 0; c < 2; ++c) {
    const int qi = wv*2 + c;
    const int n = qt*16 + qi;
    unsigned cw = cnts[qi];
    unsigned cnt = cw & 0xffffu;
    int c0q = (int)cnt - (int)(cw >> 16);

    const float qx = pos1_re[(b*3 + 0)*NN + n];
    const float qy = pos1_re[(b*3 + 1)*NN + n];
    const float qz = pos1_re[(b*3 + 2)*NN + n];
    const float q2 = __fadd_rn(__fadd_rn(__fmul_rn(qx,qx), __fmul_rn(qy,qy)), __fmul_rn(qz,qz));

    if (c0q >= 16 && cnt <= 128u) {
      const unsigned short* lst = &lists[qi << 7];
      unsigned long long key = ~0ull;
      if (lane < (int)cnt) {
        int ix = lst[lane];
        float4 r = rp[ix];
        float dot = __fadd_rn(__fadd_rn(__fmul_rn(qx,r.x), __fmul_rn(qy,r.y)), __fmul_rn(qz,r.z));
        float d   = __fsub_rn(__fadd_rn(q2, r.w), __fmul_rn(2.0f, dot));
        unsigned du = __float_as_uint(d);
        du ^= (du >> 31) ? 0xFFFFFFFFu : 0x80000000u;
        key = ((unsigned long long)du << 16) | (unsigned)ix;
      }
      #pragma unroll
      for (int k = 2; k <= 64; k <<= 1)
        #pragma unroll
        for (int j = k>>1; j > 0; j >>= 1) {
          unsigned long long p = shflxor64(key, j);
          bool keepMin = (((lane & j) == 0) == ((lane & k) == 0));
          unsigned long long mnk = key < p ? key : p, mxk = key < p ? p : key;
          key = keepMin ? mnk : mxk;
        }
      if (cnt > 64u) {
        unsigned long long k2 = ~0ull;
        if (lane + 64 < (int)cnt) {
          int ix = lst[64 + lane];
          float4 r = rp[ix];
          float dot = __fadd_rn(__fadd_rn(__fmul_rn(qx,r.x), __fmul_rn(qy,r.y)), __fmul_rn(qz,r.z));
          float d   = __fsub_rn(__fadd_rn(q2, r.w), __fmul_rn(2.0f, dot));
          unsigned du = __float_as_uint(d);
          du ^= (du >> 31) ? 0xFFFFFFFFu : 0x80000000u;
          k2 = ((unsigned long long)du << 16) | (unsigned)ix;
        }
        #pragma unroll
        for (int k = 2; k <= 64; k <<= 1)
          #pragma unroll
          for (int j = k>>1; j > 0; j >>= 1) {
            unsigned long long p = shflxor64(k2, j);
            bool keepMin = (((lane & j) == 0) == ((lane & k) == 0));
            unsigned long long mnk = k2 < p ? k2 : p, mxk = k2 < p ? p : k2;
            k2 = keepMin ? mnk : mxk;
          }
        unsigned long long pb = shfl64(k2, (15 - lane) & 63);
        key = key < pb ? key : pb;
      }
      if (lane < 16) idxOut[((size_t)(b*NN + n))*KK + lane] = (unsigned short)(key & 0xffffull);
    } else {
      // fallback: verbatim validated full scan
      unsigned bd  = 0xFFFFFFFFu;
      unsigned bix = 0u;
      unsigned tau = 0xFFFFFFFFu;
      for (int it = 0; it < 64; ++it) {
        float4 r = rp[it*64 + lane];
        float dot = __fadd_rn(__fadd_rn(__fmul_rn(qx,r.x), __fmul_rn(qy,r.y)), __fmul_rn(qz,r.z));
        float d   = __fsub_rn(__fadd_rn(q2, r.w), __fmul_rn(2.0f, dot));
        unsigned du = __float_as_uint(d);
        du ^= (du >> 31) ? 0xFFFFFFFFu : 0x80000000u;
        unsigned long long mask = __ballot(du < tau);
        while (mask) {
          const int l = __ffsll((unsigned long long)mask) - 1;
          mask &= (mask - 1);
          const unsigned sd = (unsigned)__builtin_amdgcn_readlane((int)du, l);
          if (sd >= tau) continue;
          const unsigned sidx = (unsigned)(it*64 + l);
          int m = (bd > sd) ? 1 : 0;
          int pm = __builtin_amdgcn_update_dpp(0, m, 0x111, 0xF, 0xF, true);
          unsigned sb = (unsigned)__builtin_amdgcn_update_dpp(0, (int)bd,  0x111, 0xF, 0xF, true);
          unsigned si = (unsigned)__builtin_amdgcn_update_dpp(0, (int)bix, 0x111, 0xF, 0xF, true);
          if (m) { bd = pm ? sb : sd; bix = pm ? si : sidx; }
          tau = (unsigned)__builtin_amdgcn_readlane((int)bd, 15);
        }
      }
      if (lane < 16) idxOut[((size_t)(b*NN + n))*KK + lane] = (unsigned short)bix;
    }
  }
}

// ---------- wave-level deferred stat reduce (once per wave) ----------
#define WAVE_STATS(NMT) { \
  _Pragma("unroll") \
  for (int mt = 0; mt < NMT; ++mt) { \
    _Pragma("unroll") \
    for (int rg = 0; rg < 4; ++rg) { \
      float s_ = sacc[mt][rg], q_ = sqacc[mt][rg]; \
      s_ += __shfl_xor(s_,1); s_ += __shfl_xor(s_,2); s_ += __shfl_xor(s_,4); s_ += __shfl_xor(s_,8); \
      q_ += __shfl_xor(q_,1); q_ += __shfl_xor(q_,2); q_ += __shfl_xor(q_,4); q_ += __shfl_xor(q_,8); \
      if (cl == 0) { atomicAdd(&sS[mt*16 + q*4 + rg], s_); atomicAdd(&sQ[mt*16 + q*4 + rg], q_); } \
    } \
  } }

// ---------- layer 0: gather -> MFMA, reg weights; 1D grid, b = blockIdx&7 (R11 measured-best) ----------
__global__ __launch_bounds__(256) void k_layer0(
    const unsigned short* __restrict__ nidx, const float4* __restrict__ pos2t,
    const float* __restrict__ pos1, const unsigned short* __restrict__ f2b,
    const unsigned short* __restrict__ f1b, const unsigned short* __restrict__ Apk0,
    unsigned short* __restrict__ Y0, float* __restrict__ gS, float* __restrict__ gQ) {
  __shared__ float sS[64], sQ[64];
  const int t = threadIdx.x, lane = t & 63, wv = t >> 6;
  const int b = blockIdx.x & 7, xt = blockIdx.x >> 3;
  const int n0 = xt*32 + wv*8;
  const int cl = lane & 15, q = lane >> 4;

  short8 Wr[20];
  #pragma unroll
  for (int f = 0; f < 20; ++f) Wr[f] = *(const short8*)(Apk0 + ((size_t)f*64 + lane)*8);
  if (t < 64) { sS[t] = 0.f; sQ[t] = 0.f; }
  __syncthreads();

  f32x4 sacc[4]  = {{0,0,0,0},{0,0,0,0},{0,0,0,0},{0,0,0,0}};
  f32x4 sqacc[4] = {{0,0,0,0},{0,0,0,0},{0,0,0,0},{0,0,0,0}};

  #pragma unroll 1
  for (int p = 0; p < 8; ++p) {
    const int n = n0 + p;
    const int m = (int)nidx[((size_t)(b*NN + n))*KK + cl];
    const unsigned short* f2r = f2b + ((size_t)(b*NN + m))*64;
    const unsigned short* f1r = f1b + ((size_t)(b*NN + n))*64;
    short8 x0 = *(const short8*)(f2r + q*8);
    short8 x1 = *(const short8*)(f2r + 32 + q*8);
    short8 x2 = *(const short8*)(f1r + q*8);
    short8 x3 = *(const short8*)(f1r + 32 + q*8);
    short8 x4 = {0,0,0,0,0,0,0,0};
    if (q == 0) {
      float4 pp = pos2t[(size_t)b*NN + m];
      float px = pos1[(b*3 + 0)*NN + n];
      float py = pos1[(b*3 + 1)*NN + n];
      float pz = pos1[(b*3 + 2)*NN + n];
      x4[0] = (short)f2bf(pp.x - px);
      x4[1] = (short)f2bf(pp.y - py);
      x4[2] = (short)f2bf(pp.z - pz);
    }
    f32x4 acc[4] = {{0,0,0,0},{0,0,0,0},{0,0,0,0},{0,0,0,0}};
    #pragma unroll
    for (int mt = 0; mt < 4; ++mt) {
      acc[mt] = MFMA(Wr[mt*5 + 0], x0, acc[mt]);
      acc[mt] = MFMA(Wr[mt*5 + 1], x1, acc[mt]);
      acc[mt] = MFMA(Wr[mt*5 + 2], x2, acc[mt]);
      acc[mt] = MFMA(Wr[mt*5 + 3], x3, acc[mt]);
      acc[mt] = MFMA(Wr[mt*5 + 4], x4, acc[mt]);
    }
    unsigned short* yr = Y0 + (((size_t)(b*NN + n))*KK + cl)*64;
    #pragma unroll
    for (int mt = 0; mt < 4; ++mt) {
      sacc[mt]  += acc[mt];
      sqacc[mt] += acc[mt]*acc[mt];
      ushort4 pk; pk.x = f2bf(acc[mt][0]); pk.y = f2bf(acc[mt][1]);
      pk.z = f2bf(acc[mt][2]); pk.w = f2bf(acc[mt][3]);
      *(ushort4*)(yr + mt*16 + q*4) = pk;
    }
  }
  WAVE_STATS(4)
  __syncthreads();
  const int slot = xt & 31;
  if (t < 64) { atomicAdd(&gS[slot*64 + t], sS[t]); atomicAdd(&gQ[slot*64 + t], sQ[t]); }
}

// ---------- layer 1: inline-bn0(S0,Q0)+relu(Y0) -> MFMA(64x64), reg weights ----------
__global__ __launch_bounds__(256) void k_layer1(
    const unsigned short* __restrict__ Y0, const float* __restrict__ S0, const float* __restrict__ Q0,
    const float* __restrict__ g0, const float* __restrict__ b0,
    const unsigned short* __restrict__ Apk1, unsigned short* __restrict__ Y1,
    float* __restrict__ gS, float* __restrict__ gQ) {
  __shared__ float sS[64], sQ[64];
  __shared__ float aL[64], bL[64];
  const int t = threadIdx.x, lane = t & 63, wv = t >> 6;
  const int b = blockIdx.y, n0 = blockIdx.x*32 + wv*8;
  const int cl = lane & 15, q = lane >> 4;

  short8 Wr[8];
  #pragma unroll
  for (int f = 0; f < 8; ++f) Wr[f] = *(const short8*)(Apk1 + ((size_t)f*64 + lane)*8);
  BN_INLINE(S0, Q0, g0, b0, aL, bL, 64)
  if (t >= 64 && t < 128) { sS[t-64] = 0.f; sQ[t-64] = 0.f; }
  __syncthreads();

  float ar[16], br[16];
  #pragma unroll
  for (int s = 0; s < 2; ++s)
    #pragma unroll
    for (int j = 0; j < 8; ++j) { int c = s*32 + q*8 + j; ar[s*8+j] = aL[c]; br[s*8+j] = bL[c]; }

  f32x4 sacc[4]  = {{0,0,0,0},{0,0,0,0},{0,0,0,0},{0,0,0,0}};
  f32x4 sqacc[4] = {{0,0,0,0},{0,0,0,0},{0,0,0,0},{0,0,0,0}};

  #pragma unroll 1
  for (int p = 0; p < 8; ++p) {
    const int n = n0 + p;
    const unsigned short* yr = Y0 + (((size_t)(b*NN + n))*KK + cl)*64;
    short8 u0 = *(const short8*)(yr + q*8);
    short8 u1 = *(const short8*)(yr + 32 + q*8);
    short8 x0, x1;
    #pragma unroll
    for (int j = 0; j < 8; ++j) {
      x0[j] = (short)f2bf(fmaxf(bf2f((unsigned short)u0[j])*ar[j]   + br[j],   0.f));
      x1[j] = (short)f2bf(fmaxf(bf2f((unsigned short)u1[j])*ar[8+j] + br[8+j], 0.f));
    }
    f32x4 acc[4] = {{0,0,0,0},{0,0,0,0},{0,0,0,0},{0,0,0,0}};
    #pragma unroll
    for (int mt = 0; mt < 4; ++mt) {
      acc[mt] = MFMA(Wr[mt*2 + 0], x0, acc[mt]);
      acc[mt] = MFMA(Wr[mt*2 + 1], x1, acc[mt]);
    }
    unsigned short* yw = Y1 + (((size_t)(b*NN + n))*KK + cl)*64;
    #pragma unroll
    for (int mt = 0; mt < 4; ++mt) {
      sacc[mt]  += acc[mt];
      sqacc[mt] += acc[mt]*acc[mt];
      ushort4 pk; pk.x = f2bf(acc[mt][0]); pk.y = f2bf(acc[mt][1]);
      pk.z = f2bf(acc[mt][2]); pk.w = f2bf(acc[mt][3]);
      *(ushort4*)(yw + mt*16 + q*4) = pk;
    }
  }
  WAVE_STATS(4)
  __syncthreads();
  const int slot = blockIdx.x & 31;
  if (t < 64) { atomicAdd(&gS[slot*64 + t], sS[t]); atomicAdd(&gQ[slot*64 + t], sQ[t]); }
}

// ---------- layer 2 stats + extrema: inline-bn1(S1,Q1)+relu(Y1) -> MFMA(x,W) ----------
__global__ __launch_bounds__(256) void k_l2stats(
    const unsigned short* __restrict__ Y1, const float* __restrict__ S1, const float* __restrict__ Q1,
    const float* __restrict__ g1, const float* __restrict__ b1,
    const unsigned short* __restrict__ Apk2, float2* __restrict__ Ypk,
    float* __restrict__ gS, float* __restrict__ gQ) {
  __shared__ float sS[128], sQ[128];
  __shared__ float aL[64], bL[64];
  const int t = threadIdx.x, lane = t & 63, wv = t >> 6;
  const int b = blockIdx.y, n0 = blockIdx.x*32 + wv*8;
  const int cl = lane & 15, q = lane >> 4;

  short8 Wr[16];
  #pragma unroll
  for (int f = 0; f < 16; ++f) Wr[f] = *(const short8*)(Apk2 + ((size_t)f*64 + lane)*8);
  BN_INLINE(S1, Q1, g1, b1, aL, bL, 64)
  if (t >= 64 && t < 192) { sS[t-64] = 0.f; sQ[t-64] = 0.f; }
  __syncthreads();

  float ar[16], br[16];
  #pragma unroll
  for (int s = 0; s < 2; ++s)
    #pragma unroll
    for (int j = 0; j < 8; ++j) { int c = s*32 + q*8 + j; ar[s*8+j] = aL[c]; br[s*8+j] = bL[c]; }

  float ssum[8] = {0,0,0,0,0,0,0,0};
  float sqsum[8] = {0,0,0,0,0,0,0,0};

  #pragma unroll 1
  for (int p = 0; p < 8; ++p) {
    const int n = n0 + p;
    const unsigned short* yr = Y1 + (((size_t)(b*NN + n))*KK + cl)*64;
    short8 u0 = *(const short8*)(yr + q*8);
    short8 u1 = *(const short8*)(yr + 32 + q*8);
    short8 x0, x1;
    #pragma unroll
    for (int j = 0; j < 8; ++j) {
      x0[j] = (short)f2bf(fmaxf(bf2f((unsigned short)u0[j])*ar[j]   + br[j],   0.f));
      x1[j] = (short)f2bf(fmaxf(bf2f((unsigned short)u1[j])*ar[8+j] + br[8+j], 0.f));
    }
    float2* yw = Ypk + ((size_t)(b*NN + n))*H2;
    #pragma unroll
    for (int mt = 0; mt < 8; ++mt) {
      f32x4 acc = {0,0,0,0};
      acc = MFMA(x0, Wr[mt*2 + 0], acc);     // swapped: D[k][ch]
      acc = MFMA(x1, Wr[mt*2 + 1], acc);
      ssum[mt]  += (acc[0] + acc[1]) + (acc[2] + acc[3]);
      sqsum[mt] += acc[0]*acc[0] + acc[1]*acc[1] + acc[2]*acc[2] + acc[3]*acc[3];
      float mx = fmaxf(fmaxf(acc[0], acc[1]), fmaxf(acc[2], acc[3]));
      float mn = fminf(fminf(acc[0], acc[1]), fminf(acc[2], acc[3]));
      mx = fmaxf(mx, __shfl_xor(mx, 16)); mx = fmaxf(mx, __shfl_xor(mx, 32));
      mn = fminf(mn, __shfl_xor(mn, 16)); mn = fminf(mn, __shfl_xor(mn, 32));
      if (lane < 16) yw[mt*16 + lane] = make_float2(mx, mn);
    }
  }
  #pragma unroll
  for (int mt = 0; mt < 8; ++mt) {
    float s_ = ssum[mt], q_ = sqsum[mt];
    s_ += __shfl_xor(s_, 16); s_ += __shfl_xor(s_, 32);
    q_ += __shfl_xor(q_, 16); q_ += __shfl_xor(q_, 32);
    if (lane < 16) { atomicAdd(&sS[mt*16 + cl], s_); atomicAdd(&sQ[mt*16 + cl], q_); }
  }
  __syncthreads();
  const int slot = blockIdx.x & 31;
  if (t < 128) { atomicAdd(&gS[slot*128 + t], sS[t]); atomicAdd(&gQ[slot*128 + t], sQ[t]); }
}

// ---------- final: inline-bn2(S2,Q2) + relu + (k-max via stored extrema) -> out ----------
__global__ __launch_bounds__(256) void k_bnmax(
    const float2* __restrict__ Ypk, const float* __restrict__ S2, const float* __restrict__ Q2,
    const float* __restrict__ g2, const float* __restrict__ b2,
    float* __restrict__ outF) {
  __shared__ float a2s[128], b2s[128];
  __shared__ float oBuf[32*128];   // 16 KB [np][ch]
  const int t = threadIdx.x;
  const int b = blockIdx.y, nb = blockIdx.x*32;
  BN_INLINE(S2, Q2, g2, b2, a2s, b2s, 128)
  __syncthreads();

  const float2* src = Ypk + ((size_t)(b*NN + nb))*H2;
  #pragma unroll
  for (int e = 0; e < 16; ++e) {
    int i = e*256 + t;
    float2 v = src[i];
    int ch = i & 127;
    float a = a2s[ch];
    float sel = (a >= 0.f) ? v.x : v.y;
    oBuf[i] = fmaxf(sel*a + b2s[ch], 0.f);
  }
  __syncthreads();
  {
    const int ch = t & 127, npb = (t >> 7) * 16;
    #pragma unroll
    for (int g = 0; g < 4; ++g) {
      float4 v = make_float4(oBuf[(npb + g*4 + 0)*128 + ch],
                             oBuf[(npb + g*4 + 1)*128 + ch],
                             oBuf[(npb + g*4 + 2)*128 + ch],
                             oBuf[(npb + g*4 + 3)*128 + ch]);
      *(float4*)(outF + ((size_t)(b*H2 + ch))*NN + nb + npb + g*4) = v;
    }
  }
}

// ---------- launch ----------
extern "C" void kernel_launch(void* const* d_in, const int* in_sizes, int n_in,
                              void* d_out, int out_size, void* d_ws, size_t ws_size,
                              hipStream_t stream) {
  const float* pos1    = (const float*)d_in[0];
  const float* pos1_re = (const float*)d_in[1];
  const float* pos2    = (const float*)d_in[2];
  const float* f1      = (const float*)d_in[3];
  const float* f2      = (const float*)d_in[4];
  const float* W0 = (const float*)d_in[6];
  const float* g0 = (const float*)d_in[7];
  const float* b0 = (const float*)d_in[8];
  const float* W1 = (const float*)d_in[9];
  const float* g1 = (const float*)d_in[10];
  const float* b1 = (const float*)d_in[11];
  const float* W2 = (const float*)d_in[12];
  const float* g2 = (const float*)d_in[13];
  const float* b2 = (const float*)d_in[14];
  float* out = (float*)d_out;

  // workspace layout (bytes)
  char* ws = (char*)d_ws;
  float* stats = (float*)ws;                 // 65536 B
  float* S0 = stats;         float* Q0 = stats + 2048;
  float* S1 = stats + 4096;  float* Q1 = stats + 6144;
  float* S2 = stats + 8192;  float* Q2 = stats + 12288;
  unsigned short* Apk0 = (unsigned short*)(ws + 67584);    // 20480 B (hi only used)
  unsigned short* Apk1 = (unsigned short*)(ws + 108544);   // 8192 B used
  unsigned short* Apk2 = (unsigned short*)(ws + 124928);   // 16384 B used
  unsigned short* idxb = (unsigned short*)(ws + 157696);   // 1 MB
  float4* pos2t        = (float4*)(ws + 1206272);          // 512 KB
  unsigned short* f2b  = (unsigned short*)(ws + 1730560);  // 4 MB
  unsigned short* f1b  = (unsigned short*)(ws + 5924864);  // 4 MB
  unsigned short* Y0   = (unsigned short*)(ws + 10119168); // 64 MB
  unsigned short* Y1   = (unsigned short*)(ws + 77228032); // 64 MB -> 144336896
  // KNN pack buffers alias the Y0 region (dead until k_layer0 runs, stream-ordered)
  unsigned short* ApkQ = (unsigned short*)(ws + 10119168);            // 2 MB
  unsigned short* BpkR = (unsigned short*)(ws + 10119168 + 2097152);  // 2 MB
  // y2 extrema pairs alias the Y0 region too (Y0 dead after k_layer1): 32 MB
  float2* Ypk          = (float2*)(ws + 10119168);
  if (ws_size < 144336896u) return;

  k_wt<<<dim3(11), 256, 0, stream>>>(W0, W1, W2, Apk0, Apk1, Apk2);
  k_prep<<<dim3(BB*NN/256), 256, 0, stream>>>(pos2, pos2t, pos1, out, stats);
  k_packAB<<<dim3(1024), 256, 0, stream>>>(pos1_re, pos2t, ApkQ, BpkR);
  k_transposeb2<<<dim3(NN/32, CC/32, 2*BB), dim3(32, 8), 0, stream>>>(f2, f1, f2b, f1b);
  k_knnf<<<dim3(256, BB), 512, 0, stream>>>(pos1_re, pos2t, ApkQ, BpkR, idxb);

  k_layer0<<<dim3(NN/32*BB), 256, 0, stream>>>(idxb, pos2t, pos1, f2b, f1b, Apk0, Y0, S0, Q0);
  k_layer1<<<dim3(NN/32, BB), 256, 0, stream>>>(Y0, S0, Q0, g0, b0, Apk1, Y1, S1, Q1);
  k_l2stats<<<dim3(NN/32, BB), 256, 0, stream>>>(Y1, S1, Q1, g1, b1, Apk2, Ypk, S2, Q2);
  k_bnmax<<<dim3(NN/32, BB), 256, 0, stream>>>(Ypk, S2, Q2, g2, b2, out + (size_t)BB*3*NN);
}